// Round 4
// baseline (7788.701 us; speedup 1.0000x reference)
//
#include <hip/hip_runtime.h>
#include <hip/hip_cooperative_groups.h>
#include <cmath>

namespace cg = cooperative_groups;

#define D 1024
#define DFF 4096
#define NHEADS 16
#define DH 64
#define S_CACHE 512
#define SP1 513
#define NB_L 24
#define NR_L 8
#define NCH 17

// ---- mega workspace float offsets ----
#define MW_H   0         // [2][1024]
#define MW_H2  2048      // [2][1024]
#define MW_QP  4096      // [8][2][1024]
#define MW_KP  20480     // [8][2][1024]
#define MW_VP  36864     // [8][2][1024]
#define MW_AP  53248     // [32][16][68] = 34816
#define MW_OP  88064     // [8][2][1024]
#define MW_GU  104448    // [8][2][2][4096] = 131072
#define MW_DN  235520    // [8][2][1024]
#define MW_SP  251904    // [8][2][1024]

// ---- fallback (round-2) workspace float offsets ----
#define WS_H      0
#define WS_H2     2048
#define WS_QKV    4096      // [16][3][2][1024]
#define WS_ATTN   102400    // [2][16][17][68]
#define WS_OPROJ  139392
#define WS_GU     155776
#define WS_DOWN   286848
#define WS_SPROJ  303232

__device__ __forceinline__ float silu_f(float x){ return x/(1.f+expf(-x)); }

struct MegaP {
  const float* embed; const int* position;
  const float* base_k; const float* base_v; const float* res_k; const float* res_v;
  const float* b_ln1; const float* b_ln2;
  const float* b_wq; const float* b_wk; const float* b_wv; const float* b_wo;
  const float* b_wg; const float* b_wu; const float* b_wd; const float* b_norm;
  const float* r_ln1; const float* r_ln2;
  const float* r_wq; const float* r_wk; const float* r_wv; const float* r_wo;
  const float* r_wg; const float* r_wu; const float* r_wd; const float* r_norm;
  const float* fsq_in; const float* fsq_out;
  const float* spw; const float* spb; const float* shw; const float* shb;
  float* out_fsq; float* out_rh; float* out_stop;
  float* out_bnk; float* out_bnv; float* out_rnk; float* out_rnv;
  float* ws;
};

// ===========================================================================
// MEGA: 256 blocks x 256 threads, cooperative. Each block does the A-role
// (round-3 bid) and B-role (round-3 bid+256) work per stage.
// ===========================================================================
__global__ __launch_bounds__(256, 1) void mega(MegaP p)
{
  cg::grid_group grid = cg::this_grid();
  const int bid = blockIdx.x;
  const int t = threadIdx.x;

  __shared__ float s_hn[2][D];      // 8 KB (also scratch in attn/down)
  __shared__ float s_rg[4224];      // 16.5 KB
  __shared__ float s_rw[4];

  float* ws   = p.ws;
  float* W_h  = ws + MW_H;
  float* W_h2 = ws + MW_H2;
  float* QP   = ws + MW_QP;
  float* KP   = ws + MW_KP;
  float* VP   = ws + MW_VP;
  float* AP   = ws + MW_AP;
  float* OP   = ws + MW_OP;
  float* GU   = ws + MW_GU;
  float* DN   = ws + MW_DN;
  float* SPt  = ws + MW_SP;

  // ---- role decodes ----
  const int q_ks = bid >> 5, q_jt = bid & 31;          // Q GEMV (A)
  const bool kv_isV = bid >= 128;                      // K/V GEMV (B)
  const int kv_ks = (bid & 127) >> 4, kv_jt = bid & 15;
  const int a_bh = bid & 31, a_b = a_bh >> 4, a_h = a_bh & 15;
  const int a_chA = bid >> 5, a_chB = a_chA + 8;       // attn chunks
  const int o_jt = bid & 63, ksA = bid >> 6, ksB = ksA + 4; // proj roles

  // ---- A-prefetch register buffers ----
  float4 qb[4];                      // wq / spw tile
  float4 cbK0, cbK1, cbV0, cbV1;     // chunk A cache rows
  float4 ob[2];                      // wo tile (ksA)
  float4 gb[16];                     // wg+wu tile (ksA)
  float4 db[8];                      // wd tile (ksA)

  auto PF_Q = [&](const float* wq_) {
    const int kp = t >> 3, jo4 = (t & 7) * 4;
    const int r0 = q_ks * 128 + kp * 4, c0 = q_jt * 32 + jo4;
#pragma unroll
    for (int r = 0; r < 4; ++r) qb[r] = *(const float4*)(wq_ + (size_t)(r0 + r) * D + c0);
  };
  auto PF_SP = [&]() { PF_Q(p.spw); };
  auto PF_CACHE = [&](const float* kin, const float* vin) {
    const float4* k4 = (const float4*)(kin + ((size_t)a_bh * S_CACHE + a_chA * 32) * 64);
    const float4* v4 = (const float4*)(vin + ((size_t)a_bh * S_CACHE + a_chA * 32) * 64);
    cbK0 = k4[t]; cbK1 = k4[t + 256];
    cbV0 = v4[t]; cbV1 = v4[t + 256];
  };
  auto PF_OP = [&](const float* wo_) {
    const int kp = t >> 2, jo4 = (t & 3) * 4;
    const int r0 = ksA * 128 + kp * 2, c0 = o_jt * 16 + jo4;
#pragma unroll
    for (int r = 0; r < 2; ++r) ob[r] = *(const float4*)(wo_ + (size_t)(r0 + r) * D + c0);
  };
  auto PF_GU = [&](const float* wg_, const float* wu_) {
    const int kp = t >> 4, jo4 = (t & 15) * 4;
    const int r0 = ksA * 128 + kp * 8, c0 = o_jt * 64 + jo4;
#pragma unroll
    for (int r = 0; r < 8; ++r) gb[r]     = *(const float4*)(wg_ + (size_t)(r0 + r) * DFF + c0);
#pragma unroll
    for (int r = 0; r < 8; ++r) gb[8 + r] = *(const float4*)(wu_ + (size_t)(r0 + r) * DFF + c0);
  };
  auto PF_DN = [&](const float* wd_) {
    const int kp = t >> 2, jo4 = (t & 3) * 4;
    const int r0 = ksA * 512 + kp * 8, c0 = o_jt * 16 + jo4;
#pragma unroll
    for (int r = 0; r < 8; ++r) db[r] = *(const float4*)(wd_ + (size_t)(r0 + r) * D + c0);
  };

  // ---- prologue: residual combine + rmsnorm -> s_hn ----
  auto PROLOGUE = [&](const float* hbase, const float* part, float scale,
                      const float* lnw, float* hout) {
    const int b = t >> 7, i0 = (t & 127) * 8;
    const float4* hb4 = (const float4*)(hbase + b * D + i0);
    const float4 h0 = hb4[0], h1 = hb4[1];
    float acc[8] = {h0.x, h0.y, h0.z, h0.w, h1.x, h1.y, h1.z, h1.w};
    if (part != nullptr) {
      float s0=0,s1=0,s2=0,s3=0,s4=0,s5=0,s6=0,s7=0;
      for (int ks = 0; ks < 8; ++ks) {
        const float4* p4 = (const float4*)(part + (size_t)(ks * 2 + b) * D + i0);
        const float4 a = p4[0], c = p4[1];
        s0+=a.x; s1+=a.y; s2+=a.z; s3+=a.w;
        s4+=c.x; s5+=c.y; s6+=c.z; s7+=c.w;
      }
      acc[0]+=scale*s0; acc[1]+=scale*s1; acc[2]+=scale*s2; acc[3]+=scale*s3;
      acc[4]+=scale*s4; acc[5]+=scale*s5; acc[6]+=scale*s6; acc[7]+=scale*s7;
    }
    float ssq = 0.f;
#pragma unroll
    for (int u = 0; u < 8; ++u) ssq += acc[u] * acc[u];
#pragma unroll
    for (int off = 32; off; off >>= 1) ssq += __shfl_xor(ssq, off);
    if ((t & 63) == 0) s_rw[t >> 6] = ssq;
    __syncthreads();
    const float r = rsqrtf((s_rw[b * 2] + s_rw[b * 2 + 1]) * (1.f / D) + 1e-5f);
#pragma unroll
    for (int u = 0; u < 8; ++u) s_hn[b][i0 + u] = acc[u] * r * lnw[i0 + u];
    if (hout != nullptr && bid == 0) {
      float4* o4 = (float4*)(hout + b * D + i0);
      o4[0] = make_float4(acc[0], acc[1], acc[2], acc[3]);
      o4[1] = make_float4(acc[4], acc[5], acc[6], acc[7]);
    }
    __syncthreads();
  };

  // ---- stage QKV: prologue + Q GEMV (A) + K/V GEMV (B) ----
  auto ST_QKV = [&](const float* hbase, const float* part, float scale,
                    const float* ln1, float* hout,
                    const float* wk_, const float* wv_, bool do_stop) {
    const float* WB = kv_isV ? wv_ : wk_;
    const int bkp = t >> 4, bjo4 = (t & 15) * 4;
    const int br0 = kv_ks * 128 + bkp * 8;
    const float* wbp = WB + (size_t)br0 * D + kv_jt * 64 + bjo4;
    float4 wb[8];
#pragma unroll
    for (int r = 0; r < 8; ++r) wb[r] = *(const float4*)(wbp + (size_t)r * D);
    PROLOGUE(hbase, part, scale, ln1, hout);
    {  // A: Q
      const int akp = t >> 3, ajo4 = (t & 7) * 4;
      const int ar0 = q_ks * 128 + akp * 4;
      float a00=0,a01=0,a02=0,a03=0, a10=0,a11=0,a12=0,a13=0;
#pragma unroll
      for (int r = 0; r < 4; ++r) {
        const float x0 = s_hn[0][ar0 + r], x1 = s_hn[1][ar0 + r];
        a00+=qb[r].x*x0; a01+=qb[r].y*x0; a02+=qb[r].z*x0; a03+=qb[r].w*x0;
        a10+=qb[r].x*x1; a11+=qb[r].y*x1; a12+=qb[r].z*x1; a13+=qb[r].w*x1;
      }
      s_rg[(akp*2+0)*32+ajo4+0]=a00; s_rg[(akp*2+0)*32+ajo4+1]=a01;
      s_rg[(akp*2+0)*32+ajo4+2]=a02; s_rg[(akp*2+0)*32+ajo4+3]=a03;
      s_rg[(akp*2+1)*32+ajo4+0]=a10; s_rg[(akp*2+1)*32+ajo4+1]=a11;
      s_rg[(akp*2+1)*32+ajo4+2]=a12; s_rg[(akp*2+1)*32+ajo4+3]=a13;
    }
    {  // B: K or V
      float a00=0,a01=0,a02=0,a03=0, a10=0,a11=0,a12=0,a13=0;
#pragma unroll
      for (int r = 0; r < 8; ++r) {
        const float x0 = s_hn[0][br0 + r], x1 = s_hn[1][br0 + r];
        a00+=wb[r].x*x0; a01+=wb[r].y*x0; a02+=wb[r].z*x0; a03+=wb[r].w*x0;
        a10+=wb[r].x*x1; a11+=wb[r].y*x1; a12+=wb[r].z*x1; a13+=wb[r].w*x1;
      }
      s_rg[2048+(bkp*2+0)*64+bjo4+0]=a00; s_rg[2048+(bkp*2+0)*64+bjo4+1]=a01;
      s_rg[2048+(bkp*2+0)*64+bjo4+2]=a02; s_rg[2048+(bkp*2+0)*64+bjo4+3]=a03;
      s_rg[2048+(bkp*2+1)*64+bjo4+0]=a10; s_rg[2048+(bkp*2+1)*64+bjo4+1]=a11;
      s_rg[2048+(bkp*2+1)*64+bjo4+2]=a12; s_rg[2048+(bkp*2+1)*64+bjo4+3]=a13;
    }
    __syncthreads();
    if (t < 64) {
      const int b = t >> 5, jo = t & 31;
      float s = 0.f;
#pragma unroll
      for (int k2 = 0; k2 < 32; ++k2) s += s_rg[(k2*2+b)*32+jo];
      QP[(size_t)(q_ks*2+b)*D + q_jt*32+jo] = s;
    }
    if (t < 128) {
      const int b = t >> 6, jo = t & 63;
      float s = 0.f;
#pragma unroll
      for (int k2 = 0; k2 < 16; ++k2) s += s_rg[2048+(k2*2+b)*64+jo];
      float* dst = kv_isV ? VP : KP;
      dst[(size_t)(kv_ks*2+b)*D + kv_jt*64+jo] = s;
    }
    if (do_stop && bid == 255) {
      __syncthreads();
      float acc0 = 0.f, acc1 = 0.f;
      for (int j = t; j < D; j += 256) {
        float v0 = p.spb[j], v1 = v0;
#pragma unroll
        for (int ks = 0; ks < 8; ++ks) {
          v0 += SPt[(size_t)(ks*2+0)*D + j];
          v1 += SPt[(size_t)(ks*2+1)*D + j];
        }
        const float w = p.shw[j];
        acc0 += silu_f(v0)*w; acc1 += silu_f(v1)*w;
      }
      s_rg[t] = acc0; __syncthreads();
      for (int s = 128; s > 0; s >>= 1) { if (t < s) s_rg[t] += s_rg[t+s]; __syncthreads(); }
      if (t == 0) p.out_stop[0] = s_rg[0] + p.shb[0];
      __syncthreads();
      s_rg[t] = acc1; __syncthreads();
      for (int s = 128; s > 0; s >>= 1) { if (t < s) s_rg[t] += s_rg[t+s]; __syncthreads(); }
      if (t == 0) p.out_stop[1] = s_rg[0] + p.shb[0];
    }
  };

  // ---- stage ATTN: chunks chA then chB (chB==15 handles new token) ----
  auto ST_ATTN = [&](const float* kin, const float* vin, float* kout, float* vout) {
    float* sh  = &s_hn[0][0];
    float* q   = sh;            // 64
    float* kn  = sh + 64;       // 64
    float* vn  = sh + 128;      // 64
    float* sc  = sh + 192;      // 33
    float* msl = sh + 228;      // [0]=newscore [1]=m [2]=l
    float* red8= sh + 256;      // [8][32]
    float* pvr = sh + 512;      // [16][64]
    float* skT = s_rg;          // [64][33]
    float* sv  = s_rg + 2112;   // [32][64]
    const bool hasNewB = (a_chB == 15);

    // B chunk loads (overlap with A compute)
    const float4* k4B = (const float4*)(kin + ((size_t)a_bh*S_CACHE + a_chB*32)*64);
    const float4* v4B = (const float4*)(vin + ((size_t)a_bh*S_CACHE + a_chB*32)*64);
    const float4 K2 = k4B[t], K3 = k4B[t+256], V2 = v4B[t], V3 = v4B[t+256];

    {  // A: cache-out + LDS staging
      float4* kd = (float4*)(kout + ((size_t)a_bh*SP1 + a_chA*32)*64);
      float4* vd = (float4*)(vout + ((size_t)a_bh*SP1 + a_chA*32)*64);
      kd[t]=cbK0; kd[t+256]=cbK1; vd[t]=cbV0; vd[t+256]=cbV1;
      const int key0 = t >> 4, d0 = (t & 15) * 4, key1 = 16 + key0;
      skT[(d0+0)*33+key0]=cbK0.x; skT[(d0+1)*33+key0]=cbK0.y;
      skT[(d0+2)*33+key0]=cbK0.z; skT[(d0+3)*33+key0]=cbK0.w;
      skT[(d0+0)*33+key1]=cbK1.x; skT[(d0+1)*33+key1]=cbK1.y;
      skT[(d0+2)*33+key1]=cbK1.z; skT[(d0+3)*33+key1]=cbK1.w;
      *(float4*)&sv[key0*64+d0] = cbV0;
      *(float4*)&sv[key1*64+d0] = cbV1;
    }
    if (t < 64) {
      float s = 0.f;
#pragma unroll
      for (int ks = 0; ks < 8; ++ks) s += QP[(size_t)(ks*2+a_b)*D + a_h*64 + t];
      q[t] = s;
    }
    if (hasNewB && t >= 64 && t < 128) {
      const int u = t - 64;
      float s1 = 0.f, s2 = 0.f;
#pragma unroll
      for (int ks = 0; ks < 8; ++ks) {
        s1 += KP[(size_t)(ks*2+a_b)*D + a_h*64 + u];
        s2 += VP[(size_t)(ks*2+a_b)*D + a_h*64 + u];
      }
      kn[u] = s1; vn[u] = s2;
    }
    __syncthreads();
    {
      const float pos = (float)p.position[a_b];
      if (t < 32) {
        const float inv = expf(-(float)t * 0.28782313662425575f);
        const float ang = pos * inv;
        const float c = cosf(ang), sn = sinf(ang);
        const float x1 = q[t], x2 = q[t+32];
        q[t]    = (x1*c - x2*sn) * 0.125f;
        q[t+32] = (x1*sn + x2*c) * 0.125f;
      } else if (hasNewB && t < 64) {
        const int u = t - 32;
        const float inv = expf(-(float)u * 0.28782313662425575f);
        const float ang = pos * inv;
        const float c = cosf(ang), sn = sinf(ang);
        const float x1 = kn[u], x2 = kn[u+32];
        kn[u]    = x1*c - x2*sn;
        kn[u+32] = x1*sn + x2*c;
      }
    }
    __syncthreads();
    if (hasNewB && t < 64) {
      kout[((size_t)a_bh*SP1 + S_CACHE)*64 + t] = kn[t];
      vout[((size_t)a_bh*SP1 + S_CACHE)*64 + t] = vn[t];
      float dp = q[t] * kn[t];
#pragma unroll
      for (int off = 32; off; off >>= 1) dp += __shfl_xor(dp, off);
      if (t == 0) msl[0] = dp;
    }

    auto half = [&](int ch, bool hasNew) {
      {
        const int key = t & 31, kp = t >> 5;
        float dp = 0.f;
#pragma unroll
        for (int j = 0; j < 8; ++j) dp += skT[(kp*8+j)*33+key] * q[kp*8+j];
        red8[kp*32+key] = dp;
      }
      __syncthreads();
      if (t < 32) {
        float score = 0.f;
#pragma unroll
        for (int kp = 0; kp < 8; ++kp) score += red8[kp*32+t];
        float m = score;
#pragma unroll
        for (int off = 16; off; off >>= 1) m = fmaxf(m, __shfl_xor(m, off));
        const float nsc = hasNew ? msl[0] : -1e30f;
        m = fmaxf(m, nsc);
        const float pp = expf(score - m);
        float l = pp;
#pragma unroll
        for (int off = 16; off; off >>= 1) l += __shfl_xor(l, off);
        sc[t] = pp;
        if (t == 0) {
          const float pn = hasNew ? expf(nsc - m) : 0.f;
          sc[32] = pn; msl[1] = m; msl[2] = l + pn;
        }
      }
      __syncthreads();
      {
        const int d4 = (t & 15) * 4, sp = t >> 4;
        float ax=0, ay=0, az=0, aw=0;
#pragma unroll
        for (int r = 0; r < 2; ++r) {
          const int sl = sp * 2 + r;
          const float4 vv = *(const float4*)&sv[sl*64+d4];
          const float pp = sc[sl];
          ax+=vv.x*pp; ay+=vv.y*pp; az+=vv.z*pp; aw+=vv.w*pp;
        }
        pvr[sp*64+d4+0]=ax; pvr[sp*64+d4+1]=ay; pvr[sp*64+d4+2]=az; pvr[sp*64+d4+3]=aw;
      }
      __syncthreads();
      if (t < 64) {
        float a = 0.f;
#pragma unroll
        for (int s2 = 0; s2 < 16; ++s2) a += pvr[s2*64+t];
        if (hasNew) a += sc[32] * vn[t];
        const int base = (a_bh*16 + ch) * 68;
        AP[base+2+t] = a;
        if (t == 0) { AP[base] = msl[1]; AP[base+1] = msl[2]; }
      }
    };

    half(a_chA, false);
    __syncthreads();
    {  // B: cache-out + restage
      float4* kd = (float4*)(kout + ((size_t)a_bh*SP1 + a_chB*32)*64);
      float4* vd = (float4*)(vout + ((size_t)a_bh*SP1 + a_chB*32)*64);
      kd[t]=K2; kd[t+256]=K3; vd[t]=V2; vd[t+256]=V3;
      const int key0 = t >> 4, d0 = (t & 15) * 4, key1 = 16 + key0;
      skT[(d0+0)*33+key0]=K2.x; skT[(d0+1)*33+key0]=K2.y;
      skT[(d0+2)*33+key0]=K2.z; skT[(d0+3)*33+key0]=K2.w;
      skT[(d0+0)*33+key1]=K3.x; skT[(d0+1)*33+key1]=K3.y;
      skT[(d0+2)*33+key1]=K3.z; skT[(d0+3)*33+key1]=K3.w;
      *(float4*)&sv[key0*64+d0] = V2;
      *(float4*)&sv[key1*64+d0] = V3;
    }
    __syncthreads();
    half(a_chB, hasNewB);
  };

  // ---- stage OPROJ ----
  auto ST_OPROJ = [&](const float* wo_) {
    float* cw = &s_hn[0][0];      // [2 g][2 bb][2 hr][16]
    float* oA = &s_hn[0][256];    // [2][128]
    float* oB = &s_hn[0][512];    // [2][128]
    const int kp = t >> 2, jo4 = (t & 3) * 4;
    float4 ob2[2];
#pragma unroll
    for (int r = 0; r < 2; ++r)
      ob2[r] = *(const float4*)(wo_ + (size_t)(ksB*128 + kp*2 + r)*D + o_jt*16 + jo4);
    if (t < 8) {
      const int g = t >> 2, bb = (t >> 1) & 1, hr = t & 1;
      const int hh = (g ? ksB : ksA) * 2 + hr;
      const int base = ((bb*16 + hh) * 16) * 68;
      float mg = -1e30f;
      for (int c = 0; c < 16; ++c) mg = fmaxf(mg, AP[base + c*68]);
      float lg = 0.f; float wl[16];
      for (int c = 0; c < 16; ++c) {
        const float w = expf(AP[base + c*68] - mg);
        wl[c] = w; lg += AP[base + c*68 + 1] * w;
      }
      const float invl = 1.f / lg;
      for (int c = 0; c < 16; ++c) cw[(g*4 + bb*2 + hr)*16 + c] = wl[c] * invl;
    }
    __syncthreads();
    {
      const int bb = t >> 7, ir = t & 127;
      const int iA = ksA*128 + ir, hhA = iA >> 6, hrA = hhA - ksA*2, dA = iA & 63;
      float sA = 0.f;
#pragma unroll
      for (int c = 0; c < 16; ++c)
        sA += AP[((bb*16 + hhA)*16 + c)*68 + 2 + dA] * cw[(bb*2 + hrA)*16 + c];
      oA[bb*128 + ir] = sA;
      const int iB = ksB*128 + ir, hhB = iB >> 6, hrB = hhB - ksB*2, dB = iB & 63;
      float sB = 0.f;
#pragma unroll
      for (int c = 0; c < 16; ++c)
        sB += AP[((bb*16 + hhB)*16 + c)*68 + 2 + dB] * cw[(4 + bb*2 + hrB)*16 + c];
      oB[bb*128 + ir] = sB;
    }
    __syncthreads();
    {
      float a00=0,a01=0,a02=0,a03=0, a10=0,a11=0,a12=0,a13=0;
      float b00=0,b01=0,b02=0,b03=0, b10=0,b11=0,b12=0,b13=0;
#pragma unroll
      for (int r = 0; r < 2; ++r) {
        const int ir = kp*2 + r;
        const float xa0 = oA[ir], xa1 = oA[128+ir];
        a00+=ob[r].x*xa0; a01+=ob[r].y*xa0; a02+=ob[r].z*xa0; a03+=ob[r].w*xa0;
        a10+=ob[r].x*xa1; a11+=ob[r].y*xa1; a12+=ob[r].z*xa1; a13+=ob[r].w*xa1;
        const float xb0 = oB[ir], xb1 = oB[128+ir];
        b00+=ob2[r].x*xb0; b01+=ob2[r].y*xb0; b02+=ob2[r].z*xb0; b03+=ob2[r].w*xb0;
        b10+=ob2[r].x*xb1; b11+=ob2[r].y*xb1; b12+=ob2[r].z*xb1; b13+=ob2[r].w*xb1;
      }
      s_rg[(kp*2+0)*16+jo4+0]=a00; s_rg[(kp*2+0)*16+jo4+1]=a01;
      s_rg[(kp*2+0)*16+jo4+2]=a02; s_rg[(kp*2+0)*16+jo4+3]=a03;
      s_rg[(kp*2+1)*16+jo4+0]=a10; s_rg[(kp*2+1)*16+jo4+1]=a11;
      s_rg[(kp*2+1)*16+jo4+2]=a12; s_rg[(kp*2+1)*16+jo4+3]=a13;
      s_rg[2048+(kp*2+0)*16+jo4+0]=b00; s_rg[2048+(kp*2+0)*16+jo4+1]=b01;
      s_rg[2048+(kp*2+0)*16+jo4+2]=b02; s_rg[2048+(kp*2+0)*16+jo4+3]=b03;
      s_rg[2048+(kp*2+1)*16+jo4+0]=b10; s_rg[2048+(kp*2+1)*16+jo4+1]=b11;
      s_rg[2048+(kp*2+1)*16+jo4+2]=b12; s_rg[2048+(kp*2+1)*16+jo4+3]=b13;
    }
    __syncthreads();
    if (t < 32) {
      const int b = t >> 4, jo = t & 15;
      float s = 0.f;
#pragma unroll
      for (int k2 = 0; k2 < 64; ++k2) s += s_rg[(k2*2+b)*16+jo];
      OP[(size_t)(ksA*2+b)*D + o_jt*16+jo] = s;
    } else if (t < 64) {
      const int u = t - 32, b = u >> 4, jo = u & 15;
      float s = 0.f;
#pragma unroll
      for (int k2 = 0; k2 < 64; ++k2) s += s_rg[2048+(k2*2+b)*16+jo];
      OP[(size_t)(ksB*2+b)*D + o_jt*16+jo] = s;
    }
  };

  // ---- stage GATEUP ----
  auto ST_GATEUP = [&](const float* ln2, float scale,
                       const float* wg_, const float* wu_) {
    const int kp = t >> 4, jo4 = (t & 15) * 4;
    const int brg = ksB*128 + kp*8;
    float4 gb2[16];
#pragma unroll
    for (int r = 0; r < 8; ++r)
      gb2[r]   = *(const float4*)(wg_ + (size_t)(brg + r)*DFF + o_jt*64 + jo4);
#pragma unroll
    for (int r = 0; r < 8; ++r)
      gb2[8+r] = *(const float4*)(wu_ + (size_t)(brg + r)*DFF + o_jt*64 + jo4);
    PROLOGUE(W_h, OP, scale, ln2, W_h2);
    const int arg = ksA*128 + kp*8;
    {  // A fill
      float g00=0,g01=0,g02=0,g03=0, g10=0,g11=0,g12=0,g13=0;
      float u00=0,u01=0,u02=0,u03=0, u10=0,u11=0,u12=0,u13=0;
#pragma unroll
      for (int r = 0; r < 8; ++r) {
        const float x0 = s_hn[0][arg+r], x1 = s_hn[1][arg+r];
        g00+=gb[r].x*x0; g01+=gb[r].y*x0; g02+=gb[r].z*x0; g03+=gb[r].w*x0;
        g10+=gb[r].x*x1; g11+=gb[r].y*x1; g12+=gb[r].z*x1; g13+=gb[r].w*x1;
        u00+=gb[8+r].x*x0; u01+=gb[8+r].y*x0; u02+=gb[8+r].z*x0; u03+=gb[8+r].w*x0;
        u10+=gb[8+r].x*x1; u11+=gb[8+r].y*x1; u12+=gb[8+r].z*x1; u13+=gb[8+r].w*x1;
      }
      s_rg[(kp*4+0)*64+jo4+0]=g00; s_rg[(kp*4+0)*64+jo4+1]=g01;
      s_rg[(kp*4+0)*64+jo4+2]=g02; s_rg[(kp*4+0)*64+jo4+3]=g03;
      s_rg[(kp*4+1)*64+jo4+0]=g10; s_rg[(kp*4+1)*64+jo4+1]=g11;
      s_rg[(kp*4+1)*64+jo4+2]=g12; s_rg[(kp*4+1)*64+jo4+3]=g13;
      s_rg[(kp*4+2)*64+jo4+0]=u00; s_rg[(kp*4+2)*64+jo4+1]=u01;
      s_rg[(kp*4+2)*64+jo4+2]=u02; s_rg[(kp*4+2)*64+jo4+3]=u03;
      s_rg[(kp*4+3)*64+jo4+0]=u10; s_rg[(kp*4+3)*64+jo4+1]=u11;
      s_rg[(kp*4+3)*64+jo4+2]=u12; s_rg[(kp*4+3)*64+jo4+3]=u13;
    }
    __syncthreads();
    {
      const int sel = t >> 6, jo = t & 63;
      float s = 0.f;
#pragma unroll
      for (int k2 = 0; k2 < 16; ++k2) s += s_rg[(k2*4+sel)*64+jo];
      const int gm = sel >> 1, b = sel & 1;
      GU[(size_t)((ksA*2+gm)*2+b)*DFF + o_jt*64+jo] = s;
    }
    __syncthreads();
    {  // B fill
      float g00=0,g01=0,g02=0,g03=0, g10=0,g11=0,g12=0,g13=0;
      float u00=0,u01=0,u02=0,u03=0, u10=0,u11=0,u12=0,u13=0;
#pragma unroll
      for (int r = 0; r < 8; ++r) {
        const float x0 = s_hn[0][brg+r], x1 = s_hn[1][brg+r];
        g00+=gb2[r].x*x0; g01+=gb2[r].y*x0; g02+=gb2[r].z*x0; g03+=gb2[r].w*x0;
        g10+=gb2[r].x*x1; g11+=gb2[r].y*x1; g12+=gb2[r].z*x1; g13+=gb2[r].w*x1;
        u00+=gb2[8+r].x*x0; u01+=gb2[8+r].y*x0; u02+=gb2[8+r].z*x0; u03+=gb2[8+r].w*x0;
        u10+=gb2[8+r].x*x1; u11+=gb2[8+r].y*x1; u12+=gb2[8+r].z*x1; u13+=gb2[8+r].w*x1;
      }
      s_rg[(kp*4+0)*64+jo4+0]=g00; s_rg[(kp*4+0)*64+jo4+1]=g01;
      s_rg[(kp*4+0)*64+jo4+2]=g02; s_rg[(kp*4+0)*64+jo4+3]=g03;
      s_rg[(kp*4+1)*64+jo4+0]=g10; s_rg[(kp*4+1)*64+jo4+1]=g11;
      s_rg[(kp*4+1)*64+jo4+2]=g12; s_rg[(kp*4+1)*64+jo4+3]=g13;
      s_rg[(kp*4+2)*64+jo4+0]=u00; s_rg[(kp*4+2)*64+jo4+1]=u01;
      s_rg[(kp*4+2)*64+jo4+2]=u02; s_rg[(kp*4+2)*64+jo4+3]=u03;
      s_rg[(kp*4+3)*64+jo4+0]=u10; s_rg[(kp*4+3)*64+jo4+1]=u11;
      s_rg[(kp*4+3)*64+jo4+2]=u12; s_rg[(kp*4+3)*64+jo4+3]=u13;
    }
    __syncthreads();
    {
      const int sel = t >> 6, jo = t & 63;
      float s = 0.f;
#pragma unroll
      for (int k2 = 0; k2 < 16; ++k2) s += s_rg[(k2*4+sel)*64+jo];
      const int gm = sel >> 1, b = sel & 1;
      GU[(size_t)((ksB*2+gm)*2+b)*DFF + o_jt*64+jo] = s;
    }
  };

  // ---- stage DOWN ----
  auto ST_DOWN = [&](const float* wd_) {
    const int kp = t >> 2, jo4 = (t & 3) * 4;
    float4 db2[8];
#pragma unroll
    for (int r = 0; r < 8; ++r)
      db2[r] = *(const float4*)(wd_ + (size_t)(ksB*512 + kp*8 + r)*D + o_jt*16 + jo4);
    float* actA = &s_hn[0][0];
    float* actB = &s_hn[0][1024];
#pragma unroll
    for (int u = 0; u < 4; ++u) {
      const int e = u*256 + t, b = e >> 9, ir = e & 511;
      const int iA = ksA*512 + ir;
      float g = 0.f, uu = 0.f;
#pragma unroll
      for (int k = 0; k < 8; ++k) {
        g  += GU[(size_t)((k*2+0)*2+b)*DFF + iA];
        uu += GU[(size_t)((k*2+1)*2+b)*DFF + iA];
      }
      actA[b*512+ir] = silu_f(g) * uu;
    }
#pragma unroll
    for (int u = 0; u < 4; ++u) {
      const int e = u*256 + t, b = e >> 9, ir = e & 511;
      const int iB = ksB*512 + ir;
      float g = 0.f, uu = 0.f;
#pragma unroll
      for (int k = 0; k < 8; ++k) {
        g  += GU[(size_t)((k*2+0)*2+b)*DFF + iB];
        uu += GU[(size_t)((k*2+1)*2+b)*DFF + iB];
      }
      actB[b*512+ir] = silu_f(g) * uu;
    }
    __syncthreads();
    {
      float a00=0,a01=0,a02=0,a03=0, a10=0,a11=0,a12=0,a13=0;
      float b00=0,b01=0,b02=0,b03=0, b10=0,b11=0,b12=0,b13=0;
#pragma unroll
      for (int r = 0; r < 8; ++r) {
        const int ir = kp*8 + r;
        const float xa0 = actA[ir], xa1 = actA[512+ir];
        a00+=db[r].x*xa0; a01+=db[r].y*xa0; a02+=db[r].z*xa0; a03+=db[r].w*xa0;
        a10+=db[r].x*xa1; a11+=db[r].y*xa1; a12+=db[r].z*xa1; a13+=db[r].w*xa1;
        const float xb0 = actB[ir], xb1 = actB[512+ir];
        b00+=db2[r].x*xb0; b01+=db2[r].y*xb0; b02+=db2[r].z*xb0; b03+=db2[r].w*xb0;
        b10+=db2[r].x*xb1; b11+=db2[r].y*xb1; b12+=db2[r].z*xb1; b13+=db2[r].w*xb1;
      }
      s_rg[(kp*2+0)*16+jo4+0]=a00; s_rg[(kp*2+0)*16+jo4+1]=a01;
      s_rg[(kp*2+0)*16+jo4+2]=a02; s_rg[(kp*2+0)*16+jo4+3]=a03;
      s_rg[(kp*2+1)*16+jo4+0]=a10; s_rg[(kp*2+1)*16+jo4+1]=a11;
      s_rg[(kp*2+1)*16+jo4+2]=a12; s_rg[(kp*2+1)*16+jo4+3]=a13;
      s_rg[2048+(kp*2+0)*16+jo4+0]=b00; s_rg[2048+(kp*2+0)*16+jo4+1]=b01;
      s_rg[2048+(kp*2+0)*16+jo4+2]=b02; s_rg[2048+(kp*2+0)*16+jo4+3]=b03;
      s_rg[2048+(kp*2+1)*16+jo4+0]=b10; s_rg[2048+(kp*2+1)*16+jo4+1]=b11;
      s_rg[2048+(kp*2+1)*16+jo4+2]=b12; s_rg[2048+(kp*2+1)*16+jo4+3]=b13;
    }
    __syncthreads();
    if (t < 32) {
      const int b = t >> 4, jo = t & 15;
      float s = 0.f;
#pragma unroll
      for (int k2 = 0; k2 < 64; ++k2) s += s_rg[(k2*2+b)*16+jo];
      DN[(size_t)(ksA*2+b)*D + o_jt*16+jo] = s;
    } else if (t < 64) {
      const int u = t - 32, b = u >> 4, jo = u & 15;
      float s = 0.f;
#pragma unroll
      for (int k2 = 0; k2 < 64; ++k2) s += s_rg[2048+(k2*2+b)*16+jo];
      DN[(size_t)(ksB*2+b)*D + o_jt*16+jo] = s;
    }
  };

  // ---- stage HEADS: sproj (all blocks) + fsq (bid<16) ----
  auto ST_HEADS = [&](float scale) {
    PROLOGUE(W_h2, DN, scale, p.b_norm, nullptr);
    {
      const int akp = t >> 3, ajo4 = (t & 7) * 4;
      const int ar0 = (bid >> 5)*128 + akp*4;
      float a00=0,a01=0,a02=0,a03=0, a10=0,a11=0,a12=0,a13=0;
#pragma unroll
      for (int r = 0; r < 4; ++r) {
        const float x0 = s_hn[0][ar0+r], x1 = s_hn[1][ar0+r];
        a00+=qb[r].x*x0; a01+=qb[r].y*x0; a02+=qb[r].z*x0; a03+=qb[r].w*x0;
        a10+=qb[r].x*x1; a11+=qb[r].y*x1; a12+=qb[r].z*x1; a13+=qb[r].w*x1;
      }
      s_rg[(akp*2+0)*32+ajo4+0]=a00; s_rg[(akp*2+0)*32+ajo4+1]=a01;
      s_rg[(akp*2+0)*32+ajo4+2]=a02; s_rg[(akp*2+0)*32+ajo4+3]=a03;
      s_rg[(akp*2+1)*32+ajo4+0]=a10; s_rg[(akp*2+1)*32+ajo4+1]=a11;
      s_rg[(akp*2+1)*32+ajo4+2]=a12; s_rg[(akp*2+1)*32+ajo4+3]=a13;
    }
    __syncthreads();
    if (t < 64) {
      const int b = t >> 5, jo = t & 31;
      float s = 0.f;
#pragma unroll
      for (int k2 = 0; k2 < 32; ++k2) s += s_rg[(k2*2+b)*32+jo];
      SPt[(size_t)((bid>>5)*2+b)*D + (bid&31)*32+jo] = s;
    }
    if (bid < 16) {
      __syncthreads();
      {
        const int c = t & 31, b2 = (t >> 5) & 1, kp2 = t >> 6;
        float s = 0.f;
        for (int i = kp2*256; i < kp2*256 + 256; ++i) s += s_hn[b2][i] * p.fsq_in[i*32+c];
        s_rg[(kp2*2+b2)*32+c] = s;
      }
      __syncthreads();
      if (t < 64) {
        const int b2 = t >> 5, c = t & 31;
        float z = s_rg[(0*2+b2)*32+c] + s_rg[(1*2+b2)*32+c]
                + s_rg[(2*2+b2)*32+c] + s_rg[(3*2+b2)*32+c];
        z = tanhf(z);
        s_rg[1024 + b2*32+c] = rintf(z*3.5f) / 3.5f;
      }
      __syncthreads();
      if (t < 128) {
        const int b2 = t >> 6, jo = t & 63;
        const int j = bid*64 + jo;
        float s = 0.f;
#pragma unroll
        for (int c = 0; c < 32; ++c) s += s_rg[1024 + b2*32+c] * p.fsq_out[c*D+j];
        p.out_fsq[b2*D+j] = s;
        W_h[b2*D+j] = s + p.embed[b2*D+j];
      }
    }
  };

  // ================= main sequence =================
  const float scaleB = 0.28577380332470412f;  // 1.4/sqrt(24)
  const float scaleR = 0.49497474683058329f;  // 1.4/sqrt(8)
  const size_t cacheL_in  = (size_t)2*16*S_CACHE*64;
  const size_t cacheL_out = (size_t)2*16*SP1*64;

  PF_Q(p.b_wq);

  for (int phase = 0; phase < 2; ++phase) {
    const int L = phase ? NR_L : NB_L;
    const float sc_ = phase ? scaleR : scaleB;
    const float* ln1b = phase ? p.r_ln1 : p.b_ln1;
    const float* ln2b = phase ? p.r_ln2 : p.b_ln2;
    const float* wqb = phase ? p.r_wq : p.b_wq;
    const float* wkb = phase ? p.r_wk : p.b_wk;
    const float* wvb = phase ? p.r_wv : p.b_wv;
    const float* wob = phase ? p.r_wo : p.b_wo;
    const float* wgb = phase ? p.r_wg : p.b_wg;
    const float* wub = phase ? p.r_wu : p.b_wu;
    const float* wdb = phase ? p.r_wd : p.b_wd;
    const float* kinb = phase ? p.res_k : p.base_k;
    const float* vinb = phase ? p.res_v : p.base_v;
    float* koutb = phase ? p.out_rnk : p.out_bnk;
    float* voutb = phase ? p.out_rnv : p.out_bnv;

    for (int l = 0; l < L; ++l) {
      const float* wk_ = wkb + (size_t)l*D*D;
      const float* wv_ = wvb + (size_t)l*D*D;
      const float* wo_ = wob + (size_t)l*D*D;
      const float* wg_ = wgb + (size_t)l*D*DFF;
      const float* wu_ = wub + (size_t)l*D*DFF;
      const float* wd_ = wdb + (size_t)l*DFF*D;
      const float* kin = kinb + (size_t)l*cacheL_in;
      const float* vin = vinb + (size_t)l*cacheL_in;
      float* kout = koutb + (size_t)l*cacheL_out;
      float* vout = voutb + (size_t)l*cacheL_out;
      const float* hbase; float* hout; bool hp;
      if (phase == 0) { hbase = (l==0)? p.embed : W_h2; hout = W_h; hp = (l>0); }
      else            { hbase = (l==0)? W_h : W_h2; hout = (l==0)? nullptr : W_h; hp = (l>0); }

      PF_CACHE(kin, vin);
      PF_OP(wo_);
      grid.sync();
      ST_QKV(hbase, hp ? DN : nullptr, sc_, ln1b + (size_t)l*D, hout,
             wk_, wv_, (phase==1 && l==0));
      PF_GU(wg_, wu_);
      grid.sync();
      ST_ATTN(kin, vin, kout, vout);
      PF_DN(wd_);
      grid.sync();
      ST_OPROJ(wo_);
      if (l+1 < L) PF_Q(wqb + (size_t)(l+1)*D*D);
      else if (phase == 0) PF_SP();
      grid.sync();
      ST_GATEUP(ln2b + (size_t)l*D, sc_, wg_, wu_);
      grid.sync();
      ST_DOWN(wd_);
    }
    if (phase == 0) {
      grid.sync();
      ST_HEADS(scaleB);
      PF_Q(p.r_wq);
    }
  }
  grid.sync();
  if (bid == 0) {
    PROLOGUE(W_h2, DN, scaleR, p.r_norm, nullptr);
    const int b = t >> 7, i0 = (t & 127) * 8;
#pragma unroll
    for (int u = 0; u < 8; ++u) p.out_rh[b*D + i0 + u] = s_hn[b][i0 + u];
  }
}

// ===========================================================================
// FALLBACK: round-2 multi-kernel path (proven, 1185 us)
// ===========================================================================
__device__ __forceinline__ void prologue_norm(
    const float* __restrict__ hbase,
    const float* __restrict__ part, int nks, float scale,
    const float* __restrict__ lnw,
    float (*hn)[D], float* __restrict__ hout)
{
  __shared__ float redw[4];
  const int t = threadIdx.x;
  const int b = t >> 7;
  const int i0 = (t & 127) * 8;
  const float4* hb4 = (const float4*)(hbase + b * D + i0);
  const float4 h0 = hb4[0], h1 = hb4[1];
  float acc[8] = {h0.x, h0.y, h0.z, h0.w, h1.x, h1.y, h1.z, h1.w};
  if (part != nullptr) {
    float s[8] = {0,0,0,0,0,0,0,0};
    for (int ks = 0; ks < nks; ++ks) {
      const float4* p4 = (const float4*)(part + (size_t)(ks * 2 + b) * D + i0);
      const float4 a = p4[0], c = p4[1];
      s[0]+=a.x; s[1]+=a.y; s[2]+=a.z; s[3]+=a.w;
      s[4]+=c.x; s[5]+=c.y; s[6]+=c.z; s[7]+=c.w;
    }
#pragma unroll
    for (int u = 0; u < 8; ++u) acc[u] += scale * s[u];
  }
  float ssq = 0.f;
#pragma unroll
  for (int u = 0; u < 8; ++u) ssq += acc[u] * acc[u];
#pragma unroll
  for (int off = 32; off; off >>= 1) ssq += __shfl_xor(ssq, off);
  if ((t & 63) == 0) redw[t >> 6] = ssq;
  __syncthreads();
  const float r = rsqrtf((redw[b * 2] + redw[b * 2 + 1]) * (1.f / D) + 1e-5f);
#pragma unroll
  for (int u = 0; u < 8; ++u) hn[b][i0 + u] = acc[u] * r * lnw[i0 + u];
  if (hout != nullptr && blockIdx.x == 0 && blockIdx.y == 0) {
    float4* o4 = (float4*)(hout + b * D + i0);
    o4[0] = make_float4(acc[0], acc[1], acc[2], acc[3]);
    o4[1] = make_float4(acc[4], acc[5], acc[6], acc[7]);
  }
  __syncthreads();
}

__global__ __launch_bounds__(256) void k_qkv(
    const float* __restrict__ hbase, const float* __restrict__ down_part,
    float* __restrict__ hout, const float* __restrict__ ln1,
    const float* __restrict__ wq, const float* __restrict__ wk,
    const float* __restrict__ wv,
    float* __restrict__ qkv_part, float scale, int has_prev)
{
  __shared__ float hn[2][D];
  __shared__ float redg[16][2][64];
  const int t = threadIdx.x;
  const int ks = blockIdx.x;
  const int cg = blockIdx.y;
  const int mat = cg >> 4;
  const int jbase = (cg & 15) * 64;
  const float* W = (mat == 0) ? wq : (mat == 1) ? wk : wv;
  const int jo4 = (t & 15) * 4;
  const int kp = t >> 4;
  const int ib = ks * 64 + kp * 4;
  float4 wbuf[4];
#pragma unroll
  for (int r = 0; r < 4; ++r)
    wbuf[r] = *(const float4*)(W + (size_t)(ib + r) * D + jbase + jo4);
  prologue_norm(hbase, has_prev ? down_part : nullptr, 8, scale, ln1, hn, hout);
  float a00=0,a01=0,a02=0,a03=0, a10=0,a11=0,a12=0,a13=0;
#pragma unroll
  for (int r = 0; r < 4; ++r) {
    const float x0 = hn[0][ib + r], x1 = hn[1][ib + r];
    a00 += wbuf[r].x*x0; a01 += wbuf[r].y*x0; a02 += wbuf[r].z*x0; a03 += wbuf[r].w*x0;
    a10 += wbuf[r].x*x1; a11 += wbuf[r].y*x1; a12 += wbuf[r].z*x1; a13 += wbuf[r].w*x1;
  }
  redg[kp][0][jo4+0]=a00; redg[kp][0][jo4+1]=a01; redg[kp][0][jo4+2]=a02; redg[kp][0][jo4+3]=a03;
  redg[kp][1][jo4+0]=a10; redg[kp][1][jo4+1]=a11; redg[kp][1][jo4+2]=a12; redg[kp][1][jo4+3]=a13;
  __syncthreads();
  if (t < 128) {
    const int b = t >> 6, jo = t & 63;
    float s = 0.f;
#pragma unroll
    for (int k2 = 0; k2 < 16; ++k2) s += redg[k2][b][jo];
    qkv_part[(size_t)((ks * 3 + mat) * 2 + b) * D + jbase + jo] = s;
  }
}

__global__ __launch_bounds__(256) void k_attn(
    const float* __restrict__ qkv_part, const int* __restrict__ position,
    const float* __restrict__ k_in, const float* __restrict__ v_in,
    float* __restrict__ k_out, float* __restrict__ v_out,
    float* __restrict__ attn_part)
{
  const int t = threadIdx.x;
  const int chunk = blockIdx.x;
  const int bh = blockIdx.y;
  const int b = bh >> 4, h = bh & 15;
  __shared__ float q[64];
  __shared__ float sc[32];
  __shared__ float red8[8][32];
  __shared__ float pvred[16][64];
  __shared__ float mlsh[2];
  __shared__ float kn[64], vn[64];
  const size_t row_in  = (size_t)bh * S_CACHE;
  const size_t row_out = (size_t)bh * SP1;
  const int pbase = (bh * NCH + chunk) * 68;

  if (chunk < 16) {
    const float4* ksrc = (const float4*)(k_in + (row_in + chunk * 32) * 64);
    float4*       kdst = (float4*)(k_out + (row_out + chunk * 32) * 64);
    const float4* vsrc = (const float4*)(v_in + (row_in + chunk * 32) * 64);
    float4*       vdst = (float4*)(v_out + (row_out + chunk * 32) * 64);
    const float4 kc0 = ksrc[t], kc1 = ksrc[t + 256];
    const float4 vc0 = vsrc[t], vc1 = vsrc[t + 256];
    kdst[t] = kc0; kdst[t + 256] = kc1;
    vdst[t] = vc0; vdst[t + 256] = vc1;
    if (t < 64) {
      float s = 0.f;
#pragma unroll
      for (int ks = 0; ks < 16; ++ks)
        s += qkv_part[(size_t)(ks * 6 + b) * D + h * 64 + t];
      q[t] = s;
    }
    __syncthreads();
    if (t < 32) {
      const float pos = (float)position[b];
      const float inv = expf(-(float)t * 0.28782313662425575f);
      const float ang = pos * inv;
      const float c = cosf(ang), sn = sinf(ang);
      const float x1 = q[t], x2 = q[t + 32];
      q[t]      = (x1 * c - x2 * sn) * 0.125f;
      q[t + 32] = (x1 * sn + x2 * c) * 0.125f;
    }
    __syncthreads();
    {
      const int key = t & 31, kp = t >> 5;
      const float* krow = k_in + (row_in + chunk * 32 + key) * 64 + kp * 8;
      const float4 k0 = *(const float4*)krow;
      const float4 k1 = *(const float4*)(krow + 4);
      const int d = kp * 8;
      float dp = k0.x*q[d] + k0.y*q[d+1] + k0.z*q[d+2] + k0.w*q[d+3]
               + k1.x*q[d+4] + k1.y*q[d+5] + k1.z*q[d+6] + k1.w*q[d+7];
      red8[kp][key] = dp;
    }
    __syncthreads();
    if (t < 32) {
      float score = 0.f;
#pragma unroll
      for (int k2 = 0; k2 < 8; ++k2) score += red8[k2][t];
      float m = score;
#pragma unroll
      for (int off = 16; off; off >>= 1) m = fmaxf(m, __shfl_xor(m, off));
      const float p = expf(score - m);
      float l = p;
#pragma unroll
      for (int off = 16; off; off >>= 1) l += __shfl_xor(l, off);
      sc[t] = p;
      if (t == 0) { mlsh[0] = m; mlsh[1] = l; }
    }
    __syncthreads();
    {
      const int d4 = (t & 15) * 4, sp = t >> 4;
      float ax = 0.f, ay = 0.f, az = 0.f, aw = 0.f;
#pragma unroll
      for (int r = 0; r < 2; ++r) {
        const int sl = sp * 2 + r;
        const float4 vv = *(const float4*)(v_in + (row_in + chunk * 32 + sl) * 64 + d4);
        const float p2 = sc[sl];
        ax += vv.x * p2; ay += vv.y * p2; az += vv.z * p2; aw += vv.w * p2;
      }
      pvred[sp][d4+0]=ax; pvred[sp][d4+1]=ay; pvred[sp][d4+2]=az; pvred[sp][d4+3]=aw;
    }
    __syncthreads();
    if (t < 64) {
      float a = 0.f;
#pragma unroll
      for (int s2 = 0; s2 < 16; ++s2) a += pvred[s2][t];
      attn_part[pbase + 2 + t] = a;
      if (t == 0) { attn_part[pbase + 0] = mlsh[0]; attn_part[pbase + 1] = mlsh[1]; }
    }
  } else {
    if (t < 64) {
      float skv = 0.f, svv = 0.f;
#pragma unroll
      for (int ks = 0; ks < 16; ++ks) {
        skv += qkv_part[(size_t)(ks * 6 + 2 + b) * D + h * 64 + t];
        svv += qkv_part[(size_t)(ks * 6 + 4 + b) * D + h * 64 + t];
      }
      kn[t] = skv; vn[t] = svv;
    }
    if (t < 64) {
      float s = 0.f;
#pragma unroll
      for (int ks = 0; ks < 16; ++ks)
        s += qkv_part[(size_t)(ks * 6 + b) * D + h * 64 + t];
      q[t] = s;
    }
    __syncthreads();
    if (t < 32) {
      const float pos = (float)position[b];
      const float inv = expf(-(float)t * 0.28782313662425575f);
      const float ang = pos * inv;
      const float c = cosf(ang), sn = sinf(ang);
      float x1 = kn[t], x2 = kn[t + 32];
      kn[t]      = x1 * c - x2 * sn;
      kn[t + 32] = x1 * sn + x2 * c;
      x1 = q[t]; x2 = q[t + 32];
      q[t]      = (x1 * c - x2 * sn) * 0.125f;
      q[t + 32] = (x1 * sn + x2 * c) * 0.125f;
    }
    __syncthreads();
    if (t < 64) {
      k_out[(row_out + S_CACHE) * 64 + t] = kn[t];
      v_out[(row_out + S_CACHE) * 64 + t] = vn[t];
      float dp = q[t] * kn[t];
#pragma unroll
      for (int off = 32; off; off >>= 1) dp += __shfl_xor(dp, off);
      attn_part[pbase + 2 + t] = vn[t];
      if (t == 0) { attn_part[pbase + 0] = dp; attn_part[pbase + 1] = 1.f; }
    }
  }
}

__global__ __launch_bounds__(256) void k_oproj(
    const float* __restrict__ attn_part, const float* __restrict__ wo,
    float* __restrict__ oproj_part)
{
  __shared__ float o[2][128];
  __shared__ float cw[2][2][NCH];
  __shared__ float redg[32][2][32];
  const int t = threadIdx.x;
  const int ks = blockIdx.x;
  const int cg = blockIdx.y;
  const int ibeg = ks * 128;
  const int jbase = cg * 32;
  const int jo4 = (t & 7) * 4;
  const int kp = t >> 3;
  float4 wbuf[4];
#pragma unroll
  for (int r = 0; r < 4; ++r)
    wbuf[r] = *(const float4*)(wo + (size_t)(ibeg + kp * 4 + r) * D + jbase + jo4);
  if (t < 4) {
    const int bb = t >> 1, hr = t & 1;
    const int hh = ks * 2 + hr;
    const int base = ((bb * 16 + hh) * NCH) * 68;
    float mg = -1e30f;
    for (int c = 0; c < NCH; ++c) mg = fmaxf(mg, attn_part[base + c * 68]);
    float lg = 0.f;
    float wloc[NCH];
    for (int c = 0; c < NCH; ++c) {
      const float w = expf(attn_part[base + c * 68] - mg);
      wloc[c] = w;
      lg += attn_part[base + c * 68 + 1] * w;
    }
    const float invl = 1.f / lg;
    for (int c = 0; c < NCH; ++c) cw[bb][hr][c] = wloc[c] * invl;
  }
  __syncthreads();
  {
    const int bb = t >> 7, ir = t & 127;
    const int i = ibeg + ir;
    const int hh = i >> 6, hr = hh - ks * 2, d = i & 63;
    float s = 0.f;
#pragma unroll
    for (int c = 0; c < NCH; ++c)
      s += attn_part[((bb * 16 + hh) * NCH + c) * 68 + 2 + d] * cw[bb][hr][c];
    o[bb][ir] = s;
  }
  __syncthreads();
  float a00=0,a01=0,a02=0,a03=0, a10=0,a11=0,a12=0,a13=0;
#pragma unroll
  for (int r = 0; r < 4; ++r) {
    const int ir = kp * 4 + r;
    const float x0 = o[0][ir], x1 = o[1][ir];
    a00 += wbuf[r].x*x0; a01 += wbuf[r].y*x0; a02 += wbuf[r].z*x0; a03 += wbuf[r].w*x0;
    a10 += wbuf[r].x*x1; a11 += wbuf[r].y*x1; a12 += wbuf[r].z*x1; a13 += wbuf[r].w*x1;
  }
  redg[kp][0][jo4+0]=a00; redg[kp][0][jo4+1]=a01; redg[kp][0][jo4+2]=a02; redg[kp][0][jo4+3]=a03;
  redg[kp][1][jo4+0]=a10; redg[kp][1][jo4+1]=a11; redg[kp][1][jo4+2]=a12; redg[kp][1][jo4+3]=a13;
  __syncthreads();
  if (t < 64) {
    const int b = t >> 5, jo = t & 31;
    float s = 0.f;
#pragma unroll
    for (int k2 = 0; k2 < 32; ++k2) s += redg[k2][b][jo];
    oproj_part[(size_t)(ks * 2 + b) * D + jbase + jo] = s;
  }
}

__global__ __launch_bounds__(256) void k_gateup(
    const float* __restrict__ hbase, const float* __restrict__ oproj_part,
    float* __restrict__ h2_out, const float* __restrict__ ln2,
    const float* __restrict__ wg, const float* __restrict__ wu,
    float* __restrict__ gu_part, float scale)
{
  __shared__ float hn[2][D];
  __shared__ float redg[16][4][64];
  const int t = threadIdx.x;
  const int ks = blockIdx.x;
  const int cg = blockIdx.y;
  const int jbase = cg * 64;
  const int jo4 = (t & 15) * 4;
  const int kp = t >> 4;
  const int ib = ks * 128 + kp * 8;
  float4 wgb[8];
#pragma unroll
  for (int r = 0; r < 8; ++r)
    wgb[r] = *(const float4*)(wg + (size_t)(ib + r) * DFF + jbase + jo4);
  prologue_norm(hbase, oproj_part, 8, scale, ln2, hn, h2_out);
  float g00=0,g01=0,g02=0,g03=0, g10=0,g11=0,g12=0,g13=0;
  float u00=0,u01=0,u02=0,u03=0, u10=0,u11=0,u12=0,u13=0;
#pragma unroll
  for (int r = 0; r < 8; ++r) {
    const float x0 = hn[0][ib + r], x1 = hn[1][ib + r];
    g00 += wgb[r].x*x0; g01 += wgb[r].y*x0; g02 += wgb[r].z*x0; g03 += wgb[r].w*x0;
    g10 += wgb[r].x*x1; g11 += wgb[r].y*x1; g12 += wgb[r].z*x1; g13 += wgb[r].w*x1;
  }
#pragma unroll
  for (int r = 0; r < 8; ++r) {
    const float4 c = *(const float4*)(wu + (size_t)(ib + r) * DFF + jbase + jo4);
    const float x0 = hn[0][ib + r], x1 = hn[1][ib + r];
    u00 += c.x*x0; u01 += c.y*x0; u02 += c.z*x0; u03 += c.w*x0;
    u10 += c.x*x1; u11 += c.y*x1; u12 += c.z*x1; u13 += c.w*x1;
  }
  redg[kp][0][jo4+0]=g00; redg[kp][0][jo4+1]=g01; redg[kp][0][jo4+2]=g02; redg[kp][0][jo4+3]=g03;
  redg[kp][1][jo4+0]=g10; redg[kp][1][jo4+1]=g11; redg[kp][1][jo4+2]=g12; redg[kp][1][jo4+3]=g13;
  redg[kp][2][jo4+0]=u00; redg[kp][2][jo4+1]=u01; redg[kp][2][jo4+2]=u02; redg[kp][2][jo4+3]=u03;
  redg[kp][3][jo4+0]=u10; redg[kp][3][jo4+1]=u11; redg[kp][3][jo4+2]=u12; redg[kp][3][jo4+3]=u13;
  __syncthreads();
  {
    const int sel = t >> 6;
    const int jo = t & 63;
    float s = 0.f;
#pragma unroll
    for (int k2 = 0; k2 < 16; ++k2) s += redg[k2][sel][jo];
    const int gm = sel >> 1, b = sel & 1;
    gu_part[(size_t)(ks * 4 + gm * 2 + b) * DFF + jbase + jo] = s;
  }
}

__global__ __launch_bounds__(256) void k_down(
    const float* __restrict__ gu_part, const float* __restrict__ wd,
    float* __restrict__ down_part)
{
  __shared__ float act[2][512];
  __shared__ float redg[32][2][32];
  const int t = threadIdx.x;
  const int ks = blockIdx.x;
  const int cg = blockIdx.y;
  const int ibeg = ks * 512;
  const int jbase = cg * 32;
  const int jo4 = (t & 7) * 4;
  const int kp = t >> 3;
  const int ib = kp * 16;
  float4 wbuf[8];
#pragma unroll
  for (int r = 0; r < 8; ++r)
    wbuf[r] = *(const float4*)(wd + (size_t)(ibeg + ib + r) * D + jbase + jo4);
#pragma unroll
  for (int u = 0; u < 4; ++u) {
    const int e = u * 256 + t;
    const int b = e >> 9, ir = e & 511;
    const int i = ibeg + ir;
    float g = 0.f, uu = 0.f;
#pragma unroll
    for (int k = 0; k < 8; ++k) {
      g  += gu_part[(size_t)(k * 4 + b) * DFF + i];
      uu += gu_part[(size_t)(k * 4 + 2 + b) * DFF + i];
    }
    act[b][ir] = silu_f(g) * uu;
  }
  __syncthreads();
  float a00=0,a01=0,a02=0,a03=0, a10=0,a11=0,a12=0,a13=0;
#pragma unroll
  for (int r = 0; r < 8; ++r) {
    const float x0 = act[0][ib + r], x1 = act[1][ib + r];
    a00 += wbuf[r].x*x0; a01 += wbuf[r].y*x0; a02 += wbuf[r].z*x0; a03 += wbuf[r].w*x0;
    a10 += wbuf[r].x*x1; a11 += wbuf[r].y*x1; a12 += wbuf[r].z*x1; a13 += wbuf[r].w*x1;
  }
#pragma unroll
  for (int r = 8; r < 16; ++r) {
    const float4 w = *(const float4*)(wd + (size_t)(ibeg + ib + r) * D + jbase + jo4);
    const float x0 = act[0][ib + r], x1 = act[1][ib + r];
    a00 += w.x*x0; a01 += w.y*x0; a02 += w.z*x0; a03 += w.w*x0;
    a10 += w.x*x1; a11 += w.y*x1; a12 += w.z*x1; a13 += w.w*x1;
  }
  redg[kp][0][jo4+0]=a00; redg[kp][0][jo4+1]=a01; redg[kp][0][jo4+2]=a02; redg[kp][0][jo4+3]=a03;
  redg[kp][1][jo4+0]=a10; redg[kp][1][jo4+1]=a11; redg[kp][1][jo4+2]=a12; redg[kp][1][jo4+3]=a13;
  __syncthreads();
  if (t < 64) {
    const int b = t >> 5, jo = t & 31;
    float s = 0.f;
#pragma unroll
    for (int k2 = 0; k2 < 32; ++k2) s += redg[k2][b][jo];
    down_part[(size_t)(ks * 2 + b) * D + jbase + jo] = s;
  }
}

__global__ __launch_bounds__(256) void k_heads(
    const float* __restrict__ hbase, const float* __restrict__ down_part,
    const float* __restrict__ normw, const float* __restrict__ wsp,
    float* __restrict__ sproj_part,
    const float* __restrict__ fsq_in, const float* __restrict__ fsq_out,
    const float* __restrict__ embed,
    float* __restrict__ out_fsq, float* __restrict__ h_res, float scale)
{
  __shared__ float hn[2][D];
  const int t = threadIdx.x;
  const int bid = blockIdx.x;
  if (bid < 128) {
    __shared__ float redg[16][2][64];
    const int ks = bid >> 4, cg = bid & 15;
    const int jbase = cg * 64;
    const int jo4 = (t & 15) * 4;
    const int kp = t >> 4;
    const int ib = ks * 128 + kp * 8;
    float4 wbuf[8];
#pragma unroll
    for (int r = 0; r < 8; ++r)
      wbuf[r] = *(const float4*)(wsp + (size_t)(ib + r) * D + jbase + jo4);
    prologue_norm(hbase, down_part, 8, scale, normw, hn, nullptr);
    float a00=0,a01=0,a02=0,a03=0, a10=0,a11=0,a12=0,a13=0;
#pragma unroll
    for (int r = 0; r < 8; ++r) {
      const float x0 = hn[0][ib + r], x1 = hn[1][ib + r];
      a00 += wbuf[r].x*x0; a01 += wbuf[r].y*x0; a02 += wbuf[r].z*x0; a03 += wbuf[r].w*x0;
      a10 += wbuf[r].x*x1; a11 += wbuf[r].y*x1; a12 += wbuf[r].z*x1; a13 += wbuf[r].w*x1;
    }
    redg[kp][0][jo4+0]=a00; redg[kp][0][jo4+1]=a01; redg[kp][0][jo4+2]=a02; redg[kp][0][jo4+3]=a03;
    redg[kp][1][jo4+0]=a10; redg[kp][1][jo4+1]=a11; redg[kp][1][jo4+2]=a12; redg[kp][1][jo4+3]=a13;
    __syncthreads();
    if (t < 128) {
      const int b = t >> 6, jo = t & 63;
      float s = 0.f;
#pragma unroll
      for (int k2 = 0; k2 < 16; ++k2) s += redg[k2][b][jo];
      sproj_part[(size_t)(ks * 2 + b) * D + jbase + jo] = s;
    }
  } else {
    __shared__ float zred[4][2][32];
    __shared__ float zq[2][32];
    prologue_norm(hbase, down_part, 8, scale, normw, hn, nullptr);
    {
      const int c = t & 31, b = (t >> 5) & 1, kp = t >> 6;
      float s = 0.f;
      for (int i = kp * 256; i < kp * 256 + 256; ++i) s += hn[b][i] * fsq_in[i * 32 + c];
      zred[kp][b][c] = s;
    }
    __syncthreads();
    if (t < 64) {
      const int b = t >> 5, c = t & 31;
      float z = zred[0][b][c] + zred[1][b][c] + zred[2][b][c] + zred[3][b][c];
      z = tanhf(z);
      zq[b][c] = rintf(z * 3.5f) / 3.5f;
    }
    __syncthreads();
    if (t < 128) {
      const int b = t >> 6, jo = t & 63;
      const int j = (bid - 128) * 64 + jo;
      float s = 0.f;
#pragma unroll
      for (int c = 0; c < 32; ++c) s += zq[b][c] * fsq_out[c * D + j];
      out_fsq[b * D + j] = s;
      h_res[b * D + j] = s + embed[b * D + j];
    }
  }
}

__global__ __launch_bounds__(256) void k_stophead(
    const float* __restrict__ sproj_part, const float* __restrict__ bvec,
    const float* __restrict__ hw, const float* __restrict__ hb,
    float* __restrict__ out_stop)
{
  const int t = threadIdx.x;
  float acc0 = 0.f, acc1 = 0.f;
  for (int j = t; j < D; j += 256) {
    float v0 = bvec[j], v1 = bvec[j];
#pragma unroll
    for (int ks = 0; ks < 8; ++ks) {
      v0 += sproj_part[(ks * 2 + 0) * D + j];
      v1 += sproj_part[(ks * 2 + 1) * D + j];
    }
    acc0 += silu_f(v0) * hw[j];
    acc1 += silu_f(v1) * hw[j];
  }
  __shared__ float red[256];
  red[t] = acc0;
  __syncthreads();
  for (int s = 128; s > 0; s >>= 1) { if (t < s) red[t] += red[t + s]; __syncthreads(); }
  if (t == 0) out_stop[0] = red[0] + hb[0];
  __syncthreads();
  red[t] = acc1;
  __syncthreads();
  for (int s = 128; s > 0; s >>= 1) { if (t < s) red[t] += red[t + s]; __syncthreads(); }
  if (t == 0) out_stop[1] = red[0] + hb[0];
}

__global__ __launch_bounds__(256) void k_final(
    const float* __restrict__ hbase, const float* __restrict__ down_part,
    const float* __restrict__ normw, float* __restrict__ out_rh, float scale)
{
  __shared__ float hn[2][D];
  prologue_norm(hbase, down_part, 8, scale, normw, hn, nullptr);
  const int t = threadIdx.x;
  const int b = t >> 7;
  const int i0 = (t & 127) * 8;
#pragma unroll
  for (int u = 0; u < 8; ++u) out_rh[b * D + i0 + u] = hn[b][i0 + u];
}

// ---------------------------------------------------------------------------
extern "C" void kernel_launch(void* const* d_in, const int* in_sizes, int n_in,
                              void* d_out, int out_size, void* d_ws, size_t ws_size,
                              hipStream_t stream) {
  const float* embed      = (const float*)d_in[0];
  const int*   position   = (const int*)d_in[1];
  const float* base_k     = (const float*)d_in[2];
  const float* base_v     = (const float*)d_in[3];
  const float* res_k      = (const float*)d_in[4];
  const float* res_v      = (const float*)d_in[5];
  const float* base_ln1   = (const float*)d_in[6];
  const float* base_ln2   = (const float*)d_in[7];
  const float* base_wq    = (const float*)d_in[8];
  const float* base_wk    = (const float*)d_in[9];
  const float* base_wv    = (const float*)d_in[10];
  const float* base_wo    = (const float*)d_in[11];
  const float* base_wg    = (const float*)d_in[12];
  const float* base_wu    = (const float*)d_in[13];
  const float* base_wd    = (const float*)d_in[14];
  const float* base_norm  = (const float*)d_in[15];
  const float* res_ln1    = (const float*)d_in[16];
  const float* res_ln2    = (const float*)d_in[17];
  const float* res_wq     = (const float*)d_in[18];
  const float* res_wk     = (const float*)d_in[19];
  const float* res_wv     = (const float*)d_in[20];
  const float* res_wo     = (const float*)d_in[21];
  const float* res_wg     = (const float*)d_in[22];
  const float* res_wu     = (const float*)d_in[23];
  const float* res_wd     = (const float*)d_in[24];
  const float* res_norm   = (const float*)d_in[25];
  const float* fsq_in     = (const float*)d_in[26];
  const float* fsq_out    = (const float*)d_in[27];
  const float* stop_proj_w = (const float*)d_in[28];
  const float* stop_proj_b = (const float*)d_in[29];
  const float* stop_head_w = (const float*)d_in[30];
  const float* stop_head_b = (const float*)d_in[31];

  float* out = (float*)d_out;
  float* ws = (float*)d_ws;
  const size_t cacheL_in  = (size_t)2 * NHEADS * S_CACHE * DH;
  const size_t cacheL_out = (size_t)2 * NHEADS * SP1 * DH;
  float* out_fsq  = out;
  float* out_rh   = out + 2048;
  float* out_stop = out + 4096;
  float* out_bnk  = out + 4098;
  float* out_bnv  = out_bnk + (size_t)NB_L * cacheL_out;
  float* out_rnk  = out_bnv + (size_t)NB_L * cacheL_out;
  float* out_rnv  = out_rnk + (size_t)NR_L * cacheL_out;

  // ---- try cooperative mega kernel ----
  MegaP mp;
  mp.embed = embed; mp.position = position;
  mp.base_k = base_k; mp.base_v = base_v; mp.res_k = res_k; mp.res_v = res_v;
  mp.b_ln1 = base_ln1; mp.b_ln2 = base_ln2;
  mp.b_wq = base_wq; mp.b_wk = base_wk; mp.b_wv = base_wv; mp.b_wo = base_wo;
  mp.b_wg = base_wg; mp.b_wu = base_wu; mp.b_wd = base_wd; mp.b_norm = base_norm;
  mp.r_ln1 = res_ln1; mp.r_ln2 = res_ln2;
  mp.r_wq = res_wq; mp.r_wk = res_wk; mp.r_wv = res_wv; mp.r_wo = res_wo;
  mp.r_wg = res_wg; mp.r_wu = res_wu; mp.r_wd = res_wd; mp.r_norm = res_norm;
  mp.fsq_in = fsq_in; mp.fsq_out = fsq_out;
  mp.spw = stop_proj_w; mp.spb = stop_proj_b; mp.shw = stop_head_w; mp.shb = stop_head_b;
  mp.out_fsq = out_fsq; mp.out_rh = out_rh; mp.out_stop = out_stop;
  mp.out_bnk = out_bnk; mp.out_bnv = out_bnv; mp.out_rnk = out_rnk; mp.out_rnv = out_rnv;
  mp.ws = ws;

  void* args[] = { &mp };
  hipError_t ce = hipLaunchCooperativeKernel(reinterpret_cast<void*>(mega),
                                             dim3(256), dim3(256), args, 0, stream);
  if (ce == hipSuccess) return;
  (void)hipGetLastError();   // clear sticky error, fall through to fallback

  // ---- fallback: round-2 multi-kernel path ----
  float* W_h     = ws + WS_H;
  float* W_h2    = ws + WS_H2;
  float* W_qkv   = ws + WS_QKV;
  float* W_attn  = ws + WS_ATTN;
  float* W_oproj = ws + WS_OPROJ;
  float* W_gu    = ws + WS_GU;
  float* W_down  = ws + WS_DOWN;
  float* W_sproj = ws + WS_SPROJ;

  const float scaleB = 1.4f / sqrtf((float)NB_L);
  const float scaleR = 1.4f / sqrtf((float)NR_L);

  auto run_layer = [&](const float* hbase, float* hout,
                       const float* ln1, const float* ln2,
                       const float* wq, const float* wk, const float* wv,
                       const float* wo, const float* wg, const float* wu,
                       const float* wd,
                       const float* kin, const float* vin,
                       float* kout, float* vout,
                       float scale, int has_prev) {
    k_qkv<<<dim3(16, 48), 256, 0, stream>>>(hbase, W_down, hout, ln1,
                                            wq, wk, wv, W_qkv, scale, has_prev);
    k_attn<<<dim3(NCH, 32), 256, 0, stream>>>(W_qkv, position, kin, vin, kout, vout, W_attn);
    k_oproj<<<dim3(8, 32), 256, 0, stream>>>(W_attn, wo, W_oproj);
    k_gateup<<<dim3(8, 64), 256, 0, stream>>>(W_h, W_oproj, W_h2, ln2, wg, wu, W_gu, scale);
    k_down<<<dim3(8, 32), 256, 0, stream>>>(W_gu, wd, W_down);
  };

  for (int l = 0; l < NB_L; ++l) {
    run_layer(l == 0 ? embed : W_h2, W_h,
              base_ln1 + (size_t)l * D, base_ln2 + (size_t)l * D,
              base_wq + (size_t)l * D * D, base_wk + (size_t)l * D * D,
              base_wv + (size_t)l * D * D, base_wo + (size_t)l * D * D,
              base_wg + (size_t)l * D * DFF, base_wu + (size_t)l * D * DFF,
              base_wd + (size_t)l * DFF * D,
              base_k + (size_t)l * cacheL_in, base_v + (size_t)l * cacheL_in,
              out_bnk + (size_t)l * cacheL_out, out_bnv + (size_t)l * cacheL_out,
              scaleB, l > 0);
  }

  k_heads<<<144, 256, 0, stream>>>(W_h2, W_down, base_norm, stop_proj_w, W_sproj,
                                   fsq_in, fsq_out, embed, out_fsq, W_h, scaleB);
  k_stophead<<<1, 256, 0, stream>>>(W_sproj, stop_proj_b, stop_head_w, stop_head_b, out_stop);

  for (int l = 0; l < NR_L; ++l) {
    run_layer(l == 0 ? W_h : W_h2, l == 0 ? nullptr : W_h,
              res_ln1 + (size_t)l * D, res_ln2 + (size_t)l * D,
              res_wq + (size_t)l * D * D, res_wk + (size_t)l * D * D,
              res_wv + (size_t)l * D * D, res_wo + (size_t)l * D * D,
              res_wg + (size_t)l * D * DFF, res_wu + (size_t)l * D * DFF,
              res_wd + (size_t)l * DFF * D,
              res_k + (size_t)l * cacheL_in, res_v + (size_t)l * cacheL_in,
              out_rnk + (size_t)l * cacheL_out, out_rnv + (size_t)l * cacheL_out,
              scaleR, l > 0);
  }

  k_final<<<1, 256, 0, stream>>>(W_h2, W_down, res_norm, out_rh, scaleR);
}

// Round 6
// 3010.974 us; speedup vs baseline: 2.5868x; 2.5868x over previous
//
#include <hip/hip_runtime.h>
#include <cmath>

#define D 1024
#define DFF 4096
#define NHEADS 16
#define DH 64
#define S_CACHE 512
#define SP1 513
#define NB_L 24
#define NR_L 8
#define NCH 16

typedef float v4f __attribute__((ext_vector_type(4)));

// workspace float offsets
#define WS_HN1   0        // [2][1024] normed input for qkv / heads
#define WS_HN2   2048     // [2][1024] normed input for gateup; also res_in staging
#define WS_ACCO  4096     // [2][1024] residual accumulator (attn branch)
#define WS_ACCD  6144     // [2][1024] residual accumulator (mlp branch)
#define WS_QKV   8192     // [16][3][2][1024] = 98304
#define WS_AP    106496   // [32][16][68] = 34816
#define WS_GU    141312   // [8][2][2][4096] = 131072
#define WS_SP    272384   // [8][2][1024] = 16384
#define WS_CNT   288768   // 64 ints (atomic counters)

__device__ __forceinline__ float silu_f(float x){ return x/(1.f+expf(-x)); }

// ---------------------------------------------------------------------------
// finalize helper: h = acc (already combined via atomics); write rmsnorm(h)*w
// to hn_dst and optionally raw h to acc_dst. Runs in ONE block (the last).
// ---------------------------------------------------------------------------
__device__ __forceinline__ void finalize_norm(
    const float* __restrict__ acc, const float* __restrict__ normw,
    float* __restrict__ hn_dst, float* __restrict__ acc_dst,
    float* redw)
{
  const int t = threadIdx.x;
  const int b = t >> 7, i0 = (t & 127) * 8;
  float a[8];
#pragma unroll
  for (int u = 0; u < 8; ++u) a[u] = acc[b * D + i0 + u];
  float ssq = 0.f;
#pragma unroll
  for (int u = 0; u < 8; ++u) ssq += a[u] * a[u];
#pragma unroll
  for (int off = 32; off; off >>= 1) ssq += __shfl_xor(ssq, off);
  if ((t & 63) == 0) redw[t >> 6] = ssq;
  __syncthreads();
  const float r = rsqrtf((redw[b * 2] + redw[b * 2 + 1]) * (1.f / D) + 1e-5f);
#pragma unroll
  for (int u = 0; u < 8; ++u) hn_dst[b * D + i0 + u] = a[u] * r * normw[i0 + u];
  if (acc_dst != nullptr) {
#pragma unroll
    for (int u = 0; u < 8; ++u) acc_dst[b * D + i0 + u] = a[u];
  }
}

// ---------------------------------------------------------------------------
__global__ __launch_bounds__(256) void k_init(
    const float* __restrict__ embed, const float* __restrict__ ln1,
    float* __restrict__ hn1, float* __restrict__ acc_o)
{
  __shared__ float redw[4];
  finalize_norm(embed, ln1, hn1, acc_o, redw);
}

// ---------------------------------------------------------------------------
// QKV GEMV, no prologue. grid(16,48): ks K-split (64 rows), mat=cg>>4, j-tile 64.
// ---------------------------------------------------------------------------
__global__ __launch_bounds__(256) void k_qkv(
    const float* __restrict__ hn, const float* __restrict__ wq,
    const float* __restrict__ wk, const float* __restrict__ wv,
    float* __restrict__ qkv_part)
{
  __shared__ float redg[16][2][64];
  const int t = threadIdx.x;
  const int ks = blockIdx.x;          // 0..15
  const int cg = blockIdx.y;          // 0..47
  const int mat = cg >> 4;
  const int jbase = (cg & 15) * 64;
  const float* W = (mat == 0) ? wq : (mat == 1) ? wk : wv;
  const int jo4 = (t & 15) * 4;
  const int kp = t >> 4;              // 0..15
  const int ib = ks * 64 + kp * 4;
  float4 wbuf[4];
#pragma unroll
  for (int r = 0; r < 4; ++r)
    wbuf[r] = *(const float4*)(W + (size_t)(ib + r) * D + jbase + jo4);
  float x0[4], x1[4];
#pragma unroll
  for (int r = 0; r < 4; ++r) { x0[r] = hn[ib + r]; x1[r] = hn[D + ib + r]; }
  float a00=0,a01=0,a02=0,a03=0, a10=0,a11=0,a12=0,a13=0;
#pragma unroll
  for (int r = 0; r < 4; ++r) {
    a00 += wbuf[r].x*x0[r]; a01 += wbuf[r].y*x0[r]; a02 += wbuf[r].z*x0[r]; a03 += wbuf[r].w*x0[r];
    a10 += wbuf[r].x*x1[r]; a11 += wbuf[r].y*x1[r]; a12 += wbuf[r].z*x1[r]; a13 += wbuf[r].w*x1[r];
  }
  redg[kp][0][jo4+0]=a00; redg[kp][0][jo4+1]=a01; redg[kp][0][jo4+2]=a02; redg[kp][0][jo4+3]=a03;
  redg[kp][1][jo4+0]=a10; redg[kp][1][jo4+1]=a11; redg[kp][1][jo4+2]=a12; redg[kp][1][jo4+3]=a13;
  __syncthreads();
  if (t < 128) {
    const int b = t >> 6, jo = t & 63;
    float s = 0.f;
#pragma unroll
    for (int k2 = 0; k2 < 16; ++k2) s += redg[k2][b][jo];
    qkv_part[(size_t)((ks * 3 + mat) * 2 + b) * D + jbase + jo] = s;
  }
}

// ---------------------------------------------------------------------------
// Attention. grid(16, 32): 16 chunks x 32 keys; chunk 15 also handles the new
// token. Cache copy with nontemporal stores. Partials [m,l,acc64] stride 68.
// ---------------------------------------------------------------------------
__global__ __launch_bounds__(256) void k_attn(
    const float* __restrict__ qkv_part, const int* __restrict__ position,
    const float* __restrict__ k_in, const float* __restrict__ v_in,
    float* __restrict__ k_out, float* __restrict__ v_out,
    float* __restrict__ attn_part)
{
  const int t = threadIdx.x;
  const int chunk = blockIdx.x;   // 0..15
  const int bh = blockIdx.y;      // 0..31
  const int b = bh >> 4, h = bh & 15;
  const bool hasNew = (chunk == 15);
  __shared__ float q[64], kn[64], vn[64];
  __shared__ float sc[33];
  __shared__ float red8[8][32];
  __shared__ float pvred[16][64];
  __shared__ float msl[3];
  const size_t row_in  = (size_t)bh * S_CACHE;
  const size_t row_out = (size_t)bh * SP1;
  const int pbase = (bh * NCH + chunk) * 68;

  // coalesced cache copy (32 keys x 64 dims, K and V), NT stores
  {
    const v4f* ksrc = (const v4f*)(k_in + (row_in + chunk * 32) * 64);
    const v4f* vsrc = (const v4f*)(v_in + (row_in + chunk * 32) * 64);
    v4f* kdst = (v4f*)(k_out + (row_out + chunk * 32) * 64);
    v4f* vdst = (v4f*)(v_out + (row_out + chunk * 32) * 64);
    const v4f kc0 = ksrc[t], kc1 = ksrc[t + 256];
    const v4f vc0 = vsrc[t], vc1 = vsrc[t + 256];
    __builtin_nontemporal_store(kc0, &kdst[t]);
    __builtin_nontemporal_store(kc1, &kdst[t + 256]);
    __builtin_nontemporal_store(vc0, &vdst[t]);
    __builtin_nontemporal_store(vc1, &vdst[t + 256]);
  }
  // q combine (+ k/v combine for new token)
  if (t < 64) {
    float s = 0.f;
#pragma unroll
    for (int ks = 0; ks < 16; ++ks)
      s += qkv_part[(size_t)(ks * 6 + b) * D + h * 64 + t];
    q[t] = s;
  } else if (hasNew && t < 128) {
    const int u = t - 64;
    float s = 0.f;
#pragma unroll
    for (int ks = 0; ks < 16; ++ks)
      s += qkv_part[(size_t)(ks * 6 + 2 + b) * D + h * 64 + u];
    kn[u] = s;
  } else if (hasNew && t < 192) {
    const int u = t - 128;
    float s = 0.f;
#pragma unroll
    for (int ks = 0; ks < 16; ++ks)
      s += qkv_part[(size_t)(ks * 6 + 4 + b) * D + h * 64 + u];
    vn[u] = s;
  }
  __syncthreads();
  {
    const float pos = (float)position[b];
    if (t < 32) {
      const float inv = expf(-(float)t * 0.28782313662425575f);  // ln(1e4)/32
      const float ang = pos * inv;
      const float c = cosf(ang), sn = sinf(ang);
      const float x1 = q[t], x2 = q[t + 32];
      q[t]      = (x1 * c - x2 * sn) * 0.125f;
      q[t + 32] = (x1 * sn + x2 * c) * 0.125f;
    } else if (hasNew && t < 64) {
      const int u = t - 32;
      const float inv = expf(-(float)u * 0.28782313662425575f);
      const float ang = pos * inv;
      const float c = cosf(ang), sn = sinf(ang);
      const float x1 = kn[u], x2 = kn[u + 32];
      kn[u]      = x1 * c - x2 * sn;
      kn[u + 32] = x1 * sn + x2 * c;
    }
  }
  __syncthreads();
  if (hasNew && t < 64) {
    k_out[(row_out + S_CACHE) * 64 + t] = kn[t];
    v_out[(row_out + S_CACHE) * 64 + t] = vn[t];
    float dp = q[t] * kn[t];
#pragma unroll
    for (int off = 32; off; off >>= 1) dp += __shfl_xor(dp, off);
    if (t == 0) msl[0] = dp;
  }
  // scores over 32 old keys (k_in re-read hits L1 after the copy loads)
  {
    const int key = t & 31, kp = t >> 5;
    const float* krow = k_in + (row_in + chunk * 32 + key) * 64 + kp * 8;
    const float4 k0 = *(const float4*)krow;
    const float4 k1 = *(const float4*)(krow + 4);
    const int d = kp * 8;
    float dp = k0.x*q[d] + k0.y*q[d+1] + k0.z*q[d+2] + k0.w*q[d+3]
             + k1.x*q[d+4] + k1.y*q[d+5] + k1.z*q[d+6] + k1.w*q[d+7];
    red8[kp][key] = dp;
  }
  __syncthreads();
  if (t < 32) {
    float score = 0.f;
#pragma unroll
    for (int k2 = 0; k2 < 8; ++k2) score += red8[k2][t];
    float m = score;
#pragma unroll
    for (int off = 16; off; off >>= 1) m = fmaxf(m, __shfl_xor(m, off));
    const float nsc = hasNew ? msl[0] : -1e30f;
    m = fmaxf(m, nsc);
    const float p = expf(score - m);
    float l = p;
#pragma unroll
    for (int off = 16; off; off >>= 1) l += __shfl_xor(l, off);
    sc[t] = p;
    if (t == 0) {
      const float pn = hasNew ? expf(nsc - m) : 0.f;
      sc[32] = pn; msl[1] = m; msl[2] = l + pn;
    }
  }
  __syncthreads();
  {
    const int d4 = (t & 15) * 4, sp = t >> 4;
    float ax = 0.f, ay = 0.f, az = 0.f, aw = 0.f;
#pragma unroll
    for (int r = 0; r < 2; ++r) {
      const int sl = sp * 2 + r;
      const float4 vv = *(const float4*)(v_in + (row_in + chunk * 32 + sl) * 64 + d4);
      const float p2 = sc[sl];
      ax += vv.x * p2; ay += vv.y * p2; az += vv.z * p2; aw += vv.w * p2;
    }
    pvred[sp][d4+0]=ax; pvred[sp][d4+1]=ay; pvred[sp][d4+2]=az; pvred[sp][d4+3]=aw;
  }
  __syncthreads();
  if (t < 64) {
    float a = 0.f;
#pragma unroll
    for (int s2 = 0; s2 < 16; ++s2) a += pvred[s2][t];
    if (hasNew) a += sc[32] * vn[t];
    attn_part[pbase + 2 + t] = a;
    if (t == 0) { attn_part[pbase + 0] = msl[1]; attn_part[pbase + 1] = msl[2]; }
  }
}

// ---------------------------------------------------------------------------
// O-proj. grid(8,32): ks = 128-row K-range (2 heads), j-tile 32.
// Softmax-merge 16 chunk partials, GEMV of wo, atomicAdd scaled into acc_o.
// Last block finalizes: hn2 = rmsnorm(acc_o, ln2), acc_d = acc_o copy.
// ---------------------------------------------------------------------------
__global__ __launch_bounds__(256) void k_oproj(
    const float* __restrict__ attn_part, const float* __restrict__ wo,
    float* __restrict__ acc_o, float* __restrict__ acc_d,
    float* __restrict__ hn2, const float* __restrict__ ln2,
    int* __restrict__ cnt, float scale)
{
  __shared__ float o[2][128];
  __shared__ float cw[2][2][NCH];
  __shared__ float redg[32][2][32];
  __shared__ float redw[4];
  __shared__ int s_last;
  const int t = threadIdx.x;
  const int ks = blockIdx.x;   // 0..7
  const int cg = blockIdx.y;   // 0..31
  const int ibeg = ks * 128;
  const int jbase = cg * 32;
  const int jo4 = (t & 7) * 4;
  const int kp = t >> 3;       // 0..31
  float4 wbuf[4];
#pragma unroll
  for (int r = 0; r < 4; ++r)
    wbuf[r] = *(const float4*)(wo + (size_t)(ibeg + kp * 4 + r) * D + jbase + jo4);
  if (t < 4) {
    const int bb = t >> 1, hr = t & 1;
    const int hh = ks * 2 + hr;
    const int base = ((bb * 16 + hh) * NCH) * 68;
    float mg = -1e30f;
    for (int c = 0; c < NCH; ++c) mg = fmaxf(mg, attn_part[base + c * 68]);
    float lg = 0.f;
    float wloc[NCH];
    for (int c = 0; c < NCH; ++c) {
      const float w = expf(attn_part[base + c * 68] - mg);
      wloc[c] = w;
      lg += attn_part[base + c * 68 + 1] * w;
    }
    const float invl = 1.f / lg;
    for (int c = 0; c < NCH; ++c) cw[bb][hr][c] = wloc[c] * invl;
  }
  __syncthreads();
  {
    const int bb = t >> 7, ir = t & 127;
    const int i = ibeg + ir;
    const int hh = i >> 6, hr = hh - ks * 2, d = i & 63;
    float s = 0.f;
#pragma unroll
    for (int c = 0; c < NCH; ++c)
      s += attn_part[((bb * 16 + hh) * NCH + c) * 68 + 2 + d] * cw[bb][hr][c];
    o[bb][ir] = s;
  }
  __syncthreads();
  float a00=0,a01=0,a02=0,a03=0, a10=0,a11=0,a12=0,a13=0;
#pragma unroll
  for (int r = 0; r < 4; ++r) {
    const int ir = kp * 4 + r;
    const float x0 = o[0][ir], x1 = o[1][ir];
    a00 += wbuf[r].x*x0; a01 += wbuf[r].y*x0; a02 += wbuf[r].z*x0; a03 += wbuf[r].w*x0;
    a10 += wbuf[r].x*x1; a11 += wbuf[r].y*x1; a12 += wbuf[r].z*x1; a13 += wbuf[r].w*x1;
  }
  redg[kp][0][jo4+0]=a00; redg[kp][0][jo4+1]=a01; redg[kp][0][jo4+2]=a02; redg[kp][0][jo4+3]=a03;
  redg[kp][1][jo4+0]=a10; redg[kp][1][jo4+1]=a11; redg[kp][1][jo4+2]=a12; redg[kp][1][jo4+3]=a13;
  __syncthreads();
  if (t < 64) {
    const int b = t >> 5, jo = t & 31;
    float s = 0.f;
#pragma unroll
    for (int k2 = 0; k2 < 32; ++k2) s += redg[k2][b][jo];
    atomicAdd(&acc_o[(size_t)b * D + jbase + jo], s * scale);
  }
  __threadfence();
  __syncthreads();
  if (t == 0) {
    const int old = atomicAdd(cnt, 1);
    s_last = (old == 8 * 32 - 1);
  }
  __syncthreads();
  if (s_last) {
    __threadfence();
    finalize_norm(acc_o, ln2, hn2, acc_d, redw);
  }
}

// ---------------------------------------------------------------------------
// Gate+Up GEMV, no prologue. grid(8,64): ks = 128-row K-range, j-tile 64.
// ---------------------------------------------------------------------------
__global__ __launch_bounds__(256) void k_gateup(
    const float* __restrict__ hn2, const float* __restrict__ wg,
    const float* __restrict__ wu, float* __restrict__ gu_part)
{
  __shared__ float redg[16][4][64];
  const int t = threadIdx.x;
  const int ks = blockIdx.x;   // 0..7
  const int cg = blockIdx.y;   // 0..63
  const int jbase = cg * 64;
  const int jo4 = (t & 15) * 4;
  const int kp = t >> 4;
  const int ib = ks * 128 + kp * 8;
  float4 wgb[8];
#pragma unroll
  for (int r = 0; r < 8; ++r)
    wgb[r] = *(const float4*)(wg + (size_t)(ib + r) * DFF + jbase + jo4);
  float x0[8], x1[8];
#pragma unroll
  for (int r = 0; r < 8; ++r) { x0[r] = hn2[ib + r]; x1[r] = hn2[D + ib + r]; }
  float g00=0,g01=0,g02=0,g03=0, g10=0,g11=0,g12=0,g13=0;
  float u00=0,u01=0,u02=0,u03=0, u10=0,u11=0,u12=0,u13=0;
#pragma unroll
  for (int r = 0; r < 8; ++r) {
    g00 += wgb[r].x*x0[r]; g01 += wgb[r].y*x0[r]; g02 += wgb[r].z*x0[r]; g03 += wgb[r].w*x0[r];
    g10 += wgb[r].x*x1[r]; g11 += wgb[r].y*x1[r]; g12 += wgb[r].z*x1[r]; g13 += wgb[r].w*x1[r];
  }
#pragma unroll
  for (int r = 0; r < 8; ++r) {
    const float4 c = *(const float4*)(wu + (size_t)(ib + r) * DFF + jbase + jo4);
    u00 += c.x*x0[r]; u01 += c.y*x0[r]; u02 += c.z*x0[r]; u03 += c.w*x0[r];
    u10 += c.x*x1[r]; u11 += c.y*x1[r]; u12 += c.z*x1[r]; u13 += c.w*x1[r];
  }
  redg[kp][0][jo4+0]=g00; redg[kp][0][jo4+1]=g01; redg[kp][0][jo4+2]=g02; redg[kp][0][jo4+3]=g03;
  redg[kp][1][jo4+0]=g10; redg[kp][1][jo4+1]=g11; redg[kp][1][jo4+2]=g12; redg[kp][1][jo4+3]=g13;
  redg[kp][2][jo4+0]=u00; redg[kp][2][jo4+1]=u01; redg[kp][2][jo4+2]=u02; redg[kp][2][jo4+3]=u03;
  redg[kp][3][jo4+0]=u10; redg[kp][3][jo4+1]=u11; redg[kp][3][jo4+2]=u12; redg[kp][3][jo4+3]=u13;
  __syncthreads();
  {
    const int sel = t >> 6;      // 0:g,b0 1:g,b1 2:u,b0 3:u,b1
    const int jo = t & 63;
    float s = 0.f;
#pragma unroll
    for (int k2 = 0; k2 < 16; ++k2) s += redg[k2][sel][jo];
    const int gm = sel >> 1, b = sel & 1;
    gu_part[(size_t)(ks * 4 + gm * 2 + b) * DFF + jbase + jo] = s;
  }
}

// ---------------------------------------------------------------------------
// Down GEMV. grid(16,32): ks = 256-row slice of DFF, j-tile 32.
// act = silu(g)*u combined from 8 gu splits. atomicAdd scaled into acc_d.
// Last block finalizes: hn_dst = rmsnorm(acc_d, normw), opt acc_o copy.
// ---------------------------------------------------------------------------
__global__ __launch_bounds__(256) void k_down(
    const float* __restrict__ gu_part, const float* __restrict__ wd,
    float* __restrict__ acc_d, int* __restrict__ cnt, float scale,
    const float* __restrict__ normw, float* __restrict__ hn_dst,
    float* __restrict__ acc_o_dst)
{
  __shared__ float act[2][256];
  __shared__ float redg[32][2][32];
  __shared__ float redw[4];
  __shared__ int s_last;
  const int t = threadIdx.x;
  const int ks = blockIdx.x;   // 0..15
  const int cg = blockIdx.y;   // 0..31
  const int ibeg = ks * 256;
  const int jbase = cg * 32;
  const int jo4 = (t & 7) * 4;
  const int kp = t >> 3;       // 0..31
  float4 wbuf[8];
#pragma unroll
  for (int r = 0; r < 8; ++r)
    wbuf[r] = *(const float4*)(wd + (size_t)(ibeg + kp * 8 + r) * D + jbase + jo4);
#pragma unroll
  for (int u = 0; u < 2; ++u) {
    const int e = u * 256 + t;
    const int b = e >> 8, ir = e & 255;
    const int i = ibeg + ir;
    float g = 0.f, uu = 0.f;
#pragma unroll
    for (int k = 0; k < 8; ++k) {
      g  += gu_part[(size_t)(k * 4 + b) * DFF + i];
      uu += gu_part[(size_t)(k * 4 + 2 + b) * DFF + i];
    }
    act[b][ir] = silu_f(g) * uu;
  }
  __syncthreads();
  float a00=0,a01=0,a02=0,a03=0, a10=0,a11=0,a12=0,a13=0;
#pragma unroll
  for (int r = 0; r < 8; ++r) {
    const int lr = kp * 8 + r;
    const float x0 = act[0][lr], x1 = act[1][lr];
    a00 += wbuf[r].x*x0; a01 += wbuf[r].y*x0; a02 += wbuf[r].z*x0; a03 += wbuf[r].w*x0;
    a10 += wbuf[r].x*x1; a11 += wbuf[r].y*x1; a12 += wbuf[r].z*x1; a13 += wbuf[r].w*x1;
  }
  redg[kp][0][jo4+0]=a00; redg[kp][0][jo4+1]=a01; redg[kp][0][jo4+2]=a02; redg[kp][0][jo4+3]=a03;
  redg[kp][1][jo4+0]=a10; redg[kp][1][jo4+1]=a11; redg[kp][1][jo4+2]=a12; redg[kp][1][jo4+3]=a13;
  __syncthreads();
  if (t < 64) {
    const int b = t >> 5, jo = t & 31;
    float s = 0.f;
#pragma unroll
    for (int k2 = 0; k2 < 32; ++k2) s += redg[k2][b][jo];
    atomicAdd(&acc_d[(size_t)b * D + jbase + jo], s * scale);
  }
  __threadfence();
  __syncthreads();
  if (t == 0) {
    const int old = atomicAdd(cnt, 1);
    s_last = (old == 16 * 32 - 1);
  }
  __syncthreads();
  if (s_last) {
    __threadfence();
    finalize_norm(acc_d, normw, hn_dst, acc_o_dst, redw);
  }
}

// ---------------------------------------------------------------------------
// Heads: blocks 0..127 stop-proj GEMV; blocks 128..143 FSQ head.
// Both read hn1 = lm_hidden (precomputed by down-23's finalizer).
// FSQ blocks write out_fsq and res_in = fsq + embed -> hn2 buffer.
// ---------------------------------------------------------------------------
__global__ __launch_bounds__(256) void k_heads(
    const float* __restrict__ hn1, const float* __restrict__ wsp,
    float* __restrict__ sproj_part,
    const float* __restrict__ fsq_in, const float* __restrict__ fsq_out,
    const float* __restrict__ embed,
    float* __restrict__ out_fsq, float* __restrict__ res_in)
{
  const int t = threadIdx.x;
  const int bid = blockIdx.x;
  if (bid < 128) {
    __shared__ float redg[16][2][64];
    const int ks = bid >> 4, cg = bid & 15;
    const int jbase = cg * 64;
    const int jo4 = (t & 15) * 4;
    const int kp = t >> 4;
    const int ib = ks * 128 + kp * 8;
    float4 wbuf[8];
#pragma unroll
    for (int r = 0; r < 8; ++r)
      wbuf[r] = *(const float4*)(wsp + (size_t)(ib + r) * D + jbase + jo4);
    float a00=0,a01=0,a02=0,a03=0, a10=0,a11=0,a12=0,a13=0;
#pragma unroll
    for (int r = 0; r < 8; ++r) {
      const float x0 = hn1[ib + r], x1 = hn1[D + ib + r];
      a00 += wbuf[r].x*x0; a01 += wbuf[r].y*x0; a02 += wbuf[r].z*x0; a03 += wbuf[r].w*x0;
      a10 += wbuf[r].x*x1; a11 += wbuf[r].y*x1; a12 += wbuf[r].z*x1; a13 += wbuf[r].w*x1;
    }
    redg[kp][0][jo4+0]=a00; redg[kp][0][jo4+1]=a01; redg[kp][0][jo4+2]=a02; redg[kp][0][jo4+3]=a03;
    redg[kp][1][jo4+0]=a10; redg[kp][1][jo4+1]=a11; redg[kp][1][jo4+2]=a12; redg[kp][1][jo4+3]=a13;
    __syncthreads();
    if (t < 128) {
      const int b = t >> 6, jo = t & 63;
      float s = 0.f;
#pragma unroll
      for (int k2 = 0; k2 < 16; ++k2) s += redg[k2][b][jo];
      sproj_part[(size_t)(ks * 2 + b) * D + jbase + jo] = s;
    }
  } else {
    __shared__ float zred[4][2][32];
    __shared__ float zq[2][32];
    {
      const int c = t & 31, b = (t >> 5) & 1, kp = t >> 6;
      float s = 0.f;
      for (int i = kp * 256; i < kp * 256 + 256; ++i)
        s += hn1[b * D + i] * fsq_in[i * 32 + c];
      zred[kp][b][c] = s;
    }
    __syncthreads();
    if (t < 64) {
      const int b = t >> 5, c = t & 31;
      float z = zred[0][b][c] + zred[1][b][c] + zred[2][b][c] + zred[3][b][c];
      z = tanhf(z);
      zq[b][c] = rintf(z * 3.5f) / 3.5f;
    }
    __syncthreads();
    if (t < 128) {
      const int b = t >> 6, jo = t & 63;
      const int j = (bid - 128) * 64 + jo;
      float s = 0.f;
#pragma unroll
      for (int c = 0; c < 32; ++c) s += zq[b][c] * fsq_out[c * D + j];
      out_fsq[b * D + j] = s;
      res_in[b * D + j] = s + embed[b * D + j];
    }
  }
}

// ---------------------------------------------------------------------------
// Stop head + res-phase init: combine sproj partials -> logits; then
// hn1 = rmsnorm(res_in, r_ln1[0]), acc_o = res_in.
// ---------------------------------------------------------------------------
__global__ __launch_bounds__(256) void k_stophead(
    const float* __restrict__ sproj_part, const float* __restrict__ bvec,
    const float* __restrict__ hw, const float* __restrict__ hb,
    float* __restrict__ out_stop,
    const float* __restrict__ res_in, const float* __restrict__ r_ln1_0,
    float* __restrict__ hn1, float* __restrict__ acc_o)
{
  const int t = threadIdx.x;
  __shared__ float red[256];
  __shared__ float redw[4];
  float acc0 = 0.f, acc1 = 0.f;
  for (int j = t; j < D; j += 256) {
    float v0 = bvec[j], v1 = bvec[j];
#pragma unroll
    for (int ks = 0; ks < 8; ++ks) {
      v0 += sproj_part[(ks * 2 + 0) * D + j];
      v1 += sproj_part[(ks * 2 + 1) * D + j];
    }
    acc0 += silu_f(v0) * hw[j];
    acc1 += silu_f(v1) * hw[j];
  }
  red[t] = acc0;
  __syncthreads();
  for (int s = 128; s > 0; s >>= 1) { if (t < s) red[t] += red[t + s]; __syncthreads(); }
  if (t == 0) out_stop[0] = red[0] + hb[0];
  __syncthreads();
  red[t] = acc1;
  __syncthreads();
  for (int s = 128; s > 0; s >>= 1) { if (t < s) red[t] += red[t + s]; __syncthreads(); }
  if (t == 0) out_stop[1] = red[0] + hb[0];
  __syncthreads();
  finalize_norm(res_in, r_ln1_0, hn1, acc_o, redw);
}

// ---------------------------------------------------------------------------
extern "C" void kernel_launch(void* const* d_in, const int* in_sizes, int n_in,
                              void* d_out, int out_size, void* d_ws, size_t ws_size,
                              hipStream_t stream) {
  const float* embed      = (const float*)d_in[0];
  const int*   position   = (const int*)d_in[1];
  const float* base_k     = (const float*)d_in[2];
  const float* base_v     = (const float*)d_in[3];
  const float* res_k      = (const float*)d_in[4];
  const float* res_v      = (const float*)d_in[5];
  const float* base_ln1   = (const float*)d_in[6];
  const float* base_ln2   = (const float*)d_in[7];
  const float* base_wq    = (const float*)d_in[8];
  const float* base_wk    = (const float*)d_in[9];
  const float* base_wv    = (const float*)d_in[10];
  const float* base_wo    = (const float*)d_in[11];
  const float* base_wg    = (const float*)d_in[12];
  const float* base_wu    = (const float*)d_in[13];
  const float* base_wd    = (const float*)d_in[14];
  const float* base_norm  = (const float*)d_in[15];
  const float* res_ln1    = (const float*)d_in[16];
  const float* res_ln2    = (const float*)d_in[17];
  const float* res_wq     = (const float*)d_in[18];
  const float* res_wk     = (const float*)d_in[19];
  const float* res_wv     = (const float*)d_in[20];
  const float* res_wo     = (const float*)d_in[21];
  const float* res_wg     = (const float*)d_in[22];
  const float* res_wu     = (const float*)d_in[23];
  const float* res_wd     = (const float*)d_in[24];
  const float* res_norm   = (const float*)d_in[25];
  const float* fsq_in     = (const float*)d_in[26];
  const float* fsq_out    = (const float*)d_in[27];
  const float* stop_proj_w = (const float*)d_in[28];
  const float* stop_proj_b = (const float*)d_in[29];
  const float* stop_head_w = (const float*)d_in[30];
  const float* stop_head_b = (const float*)d_in[31];

  float* out = (float*)d_out;
  float* ws  = (float*)d_ws;
  float* HN1  = ws + WS_HN1;
  float* HN2  = ws + WS_HN2;
  float* ACCO = ws + WS_ACCO;
  float* ACCD = ws + WS_ACCD;
  float* QKV  = ws + WS_QKV;
  float* AP   = ws + WS_AP;
  float* GU   = ws + WS_GU;
  float* SP   = ws + WS_SP;
  int*   CNT  = (int*)(ws + WS_CNT);

  const size_t cacheL_in  = (size_t)2 * NHEADS * S_CACHE * DH;   // 1048576
  const size_t cacheL_out = (size_t)2 * NHEADS * SP1 * DH;       // 1050624
  float* out_fsq  = out;
  float* out_rh   = out + 2048;
  float* out_stop = out + 4096;
  float* out_bnk  = out + 4098;
  float* out_bnv  = out_bnk + (size_t)NB_L * cacheL_out;
  float* out_rnk  = out_bnv + (size_t)NB_L * cacheL_out;
  float* out_rnv  = out_rnk + (size_t)NR_L * cacheL_out;

  const float scaleB = 1.4f / sqrtf((float)NB_L);
  const float scaleR = 1.4f / sqrtf((float)NR_L);

  (void)hipMemsetAsync(CNT, 0, 64 * sizeof(int), stream);
  k_init<<<1, 256, 0, stream>>>(embed, base_ln1, HN1, ACCO);

  // ---- base phase ----
  for (int l = 0; l < NB_L; ++l) {
    const float* wq_ = base_wq + (size_t)l * D * D;
    const float* wk_ = base_wk + (size_t)l * D * D;
    const float* wv_ = base_wv + (size_t)l * D * D;
    const float* wo_ = base_wo + (size_t)l * D * D;
    const float* wg_ = base_wg + (size_t)l * D * DFF;
    const float* wu_ = base_wu + (size_t)l * D * DFF;
    const float* wd_ = base_wd + (size_t)l * DFF * D;
    k_qkv<<<dim3(16, 48), 256, 0, stream>>>(HN1, wq_, wk_, wv_, QKV);
    k_attn<<<dim3(16, 32), 256, 0, stream>>>(QKV, position,
        base_k + (size_t)l * cacheL_in, base_v + (size_t)l * cacheL_in,
        out_bnk + (size_t)l * cacheL_out, out_bnv + (size_t)l * cacheL_out, AP);
    k_oproj<<<dim3(8, 32), 256, 0, stream>>>(AP, wo_, ACCO, ACCD, HN2,
        base_ln2 + (size_t)l * D, CNT + 2 * l, scaleB);
    k_gateup<<<dim3(8, 64), 256, 0, stream>>>(HN2, wg_, wu_, GU);
    const float* nextw = (l + 1 < NB_L) ? (base_ln1 + (size_t)(l + 1) * D) : base_norm;
    float* accod = (l + 1 < NB_L) ? ACCO : nullptr;
    k_down<<<dim3(16, 32), 256, 0, stream>>>(GU, wd_, ACCD, CNT + 2 * l + 1,
        scaleB, nextw, HN1, accod);
  }

  k_heads<<<144, 256, 0, stream>>>(HN1, stop_proj_w, SP, fsq_in, fsq_out,
                                   embed, out_fsq, HN2);
  k_stophead<<<1, 256, 0, stream>>>(SP, stop_proj_b, stop_head_w, stop_head_b,
                                    out_stop, HN2, res_ln1, HN1, ACCO);

  // ---- res phase ----
  for (int l = 0; l < NR_L; ++l) {
    const int lg = NB_L + l;
    const float* wq_ = res_wq + (size_t)l * D * D;
    const float* wk_ = res_wk + (size_t)l * D * D;
    const float* wv_ = res_wv + (size_t)l * D * D;
    const float* wo_ = res_wo + (size_t)l * D * D;
    const float* wg_ = res_wg + (size_t)l * D * DFF;
    const float* wu_ = res_wu + (size_t)l * D * DFF;
    const float* wd_ = res_wd + (size_t)l * DFF * D;
    k_qkv<<<dim3(16, 48), 256, 0, stream>>>(HN1, wq_, wk_, wv_, QKV);
    k_attn<<<dim3(16, 32), 256, 0, stream>>>(QKV, position,
        res_k + (size_t)l * cacheL_in, res_v + (size_t)l * cacheL_in,
        out_rnk + (size_t)l * cacheL_out, out_rnv + (size_t)l * cacheL_out, AP);
    k_oproj<<<dim3(8, 32), 256, 0, stream>>>(AP, wo_, ACCO, ACCD, HN2,
        res_ln2 + (size_t)l * D, CNT + 2 * lg, scaleR);
    k_gateup<<<dim3(8, 64), 256, 0, stream>>>(HN2, wg_, wu_, GU);
    if (l + 1 < NR_L) {
      k_down<<<dim3(16, 32), 256, 0, stream>>>(GU, wd_, ACCD, CNT + 2 * lg + 1,
          scaleR, res_ln1 + (size_t)(l + 1) * D, HN1, ACCO);
    } else {
      k_down<<<dim3(16, 32), 256, 0, stream>>>(GU, wd_, ACCD, CNT + 2 * lg + 1,
          scaleR, res_norm, out_rh, nullptr);
    }
  }
}

// Round 7
// 1161.557 us; speedup vs baseline: 6.7054x; 2.5922x over previous
//
#include <hip/hip_runtime.h>
#include <cmath>

#define D 1024
#define DFF 4096
#define NHEADS 16
#define DH 64
#define S_CACHE 512
#define SP1 513
#define NB_L 24
#define NR_L 8
#define NCH 16

typedef float v4f __attribute__((ext_vector_type(4)));

// workspace layout (float offsets)
#define WS_H      0         // [2][1024]
#define WS_H2     2048      // [2][1024]
#define WS_QKV    4096      // [16][3][2][1024] = 98304
#define WS_ATTN   102400    // [2][16][16][68]  = 34816
#define WS_OPROJ  139392    // [8][2][1024]     = 16384
#define WS_GU     155776    // [8][2][2][4096]  = 131072
#define WS_DOWN   286848    // [8][2][1024]     = 16384
#define WS_SPROJ  303232    // [8][2][1024]     = 16384

__device__ __forceinline__ float silu_f(float x){ return x/(1.f+expf(-x)); }

// ---------------------------------------------------------------------------
// prologue: h = hbase (+ scale * sum_ks part) -> rmsnorm(lnw) -> hn (LDS).
// Wave-shuffle reduction: 2 barriers. block(0,0) optionally writes raw h.
// ---------------------------------------------------------------------------
__device__ __forceinline__ void prologue_norm(
    const float* __restrict__ hbase,
    const float* __restrict__ part, int nks, float scale,
    const float* __restrict__ lnw,
    float (*hn)[D], float* __restrict__ hout)
{
  __shared__ float redw[4];
  const int t = threadIdx.x;
  const int b = t >> 7;
  const int i0 = (t & 127) * 8;
  const float4* hb4 = (const float4*)(hbase + b * D + i0);
  const float4 h0 = hb4[0], h1 = hb4[1];
  float acc[8] = {h0.x, h0.y, h0.z, h0.w, h1.x, h1.y, h1.z, h1.w};
  if (part != nullptr) {
    float s[8] = {0,0,0,0,0,0,0,0};
    for (int ks = 0; ks < nks; ++ks) {
      const float4* p4 = (const float4*)(part + (size_t)(ks * 2 + b) * D + i0);
      const float4 a = p4[0], c = p4[1];
      s[0]+=a.x; s[1]+=a.y; s[2]+=a.z; s[3]+=a.w;
      s[4]+=c.x; s[5]+=c.y; s[6]+=c.z; s[7]+=c.w;
    }
#pragma unroll
    for (int u = 0; u < 8; ++u) acc[u] += scale * s[u];
  }
  float ssq = 0.f;
#pragma unroll
  for (int u = 0; u < 8; ++u) ssq += acc[u] * acc[u];
#pragma unroll
  for (int off = 32; off; off >>= 1) ssq += __shfl_xor(ssq, off);
  if ((t & 63) == 0) redw[t >> 6] = ssq;
  __syncthreads();
  const float r = rsqrtf((redw[b * 2] + redw[b * 2 + 1]) * (1.f / D) + 1e-5f);
#pragma unroll
  for (int u = 0; u < 8; ++u) hn[b][i0 + u] = acc[u] * r * lnw[i0 + u];
  if (hout != nullptr && blockIdx.x == 0 && blockIdx.y == 0) {
    float4* o4 = (float4*)(hout + b * D + i0);
    o4[0] = make_float4(acc[0], acc[1], acc[2], acc[3]);
    o4[1] = make_float4(acc[4], acc[5], acc[6], acc[7]);
  }
  __syncthreads();
}

// ---------------------------------------------------------------------------
// QKV GEMV. grid(16, 48): ks = K-split (64 rows), mat = cg>>4, j-tile 64.
// Weight tile preloaded into regs before prologue (overlap HBM with combine).
// ---------------------------------------------------------------------------
__global__ __launch_bounds__(256) void k_qkv(
    const float* __restrict__ hbase, const float* __restrict__ down_part,
    float* __restrict__ hout, const float* __restrict__ ln1,
    const float* __restrict__ wq, const float* __restrict__ wk,
    const float* __restrict__ wv,
    float* __restrict__ qkv_part, float scale, int has_prev)
{
  __shared__ float hn[2][D];
  __shared__ float redg[16][2][64];
  const int t = threadIdx.x;
  const int ks = blockIdx.x;          // 0..15
  const int cg = blockIdx.y;          // 0..47
  const int mat = cg >> 4;
  const int jbase = (cg & 15) * 64;
  const float* W = (mat == 0) ? wq : (mat == 1) ? wk : wv;
  const int jo4 = (t & 15) * 4;
  const int kp = t >> 4;              // 0..15
  const int ib = ks * 64 + kp * 4;
  float4 wbuf[4];
#pragma unroll
  for (int r = 0; r < 4; ++r)
    wbuf[r] = *(const float4*)(W + (size_t)(ib + r) * D + jbase + jo4);
  prologue_norm(hbase, has_prev ? down_part : nullptr, 8, scale, ln1, hn, hout);
  float a00=0,a01=0,a02=0,a03=0, a10=0,a11=0,a12=0,a13=0;
#pragma unroll
  for (int r = 0; r < 4; ++r) {
    const float x0 = hn[0][ib + r], x1 = hn[1][ib + r];
    a00 += wbuf[r].x*x0; a01 += wbuf[r].y*x0; a02 += wbuf[r].z*x0; a03 += wbuf[r].w*x0;
    a10 += wbuf[r].x*x1; a11 += wbuf[r].y*x1; a12 += wbuf[r].z*x1; a13 += wbuf[r].w*x1;
  }
  redg[kp][0][jo4+0]=a00; redg[kp][0][jo4+1]=a01; redg[kp][0][jo4+2]=a02; redg[kp][0][jo4+3]=a03;
  redg[kp][1][jo4+0]=a10; redg[kp][1][jo4+1]=a11; redg[kp][1][jo4+2]=a12; redg[kp][1][jo4+3]=a13;
  __syncthreads();
  if (t < 128) {
    const int b = t >> 6, jo = t & 63;
    float s = 0.f;
#pragma unroll
    for (int k2 = 0; k2 < 16; ++k2) s += redg[k2][b][jo];
    qkv_part[(size_t)((ks * 3 + mat) * 2 + b) * D + jbase + jo] = s;
  }
}

// ---------------------------------------------------------------------------
// Attention. grid(16, 32): 16 chunks x 32 keys; chunk 15 also handles the new
// token. Cache copy with nontemporal stores. Partials [m,l,acc64] stride 68.
// ---------------------------------------------------------------------------
__global__ __launch_bounds__(256) void k_attn(
    const float* __restrict__ qkv_part, const int* __restrict__ position,
    const float* __restrict__ k_in, const float* __restrict__ v_in,
    float* __restrict__ k_out, float* __restrict__ v_out,
    float* __restrict__ attn_part)
{
  const int t = threadIdx.x;
  const int chunk = blockIdx.x;   // 0..15
  const int bh = blockIdx.y;      // 0..31
  const int b = bh >> 4, h = bh & 15;
  const bool hasNew = (chunk == 15);
  __shared__ float q[64], kn[64], vn[64];
  __shared__ float sc[33];
  __shared__ float red8[8][32];
  __shared__ float pvred[16][64];
  __shared__ float msl[3];
  const size_t row_in  = (size_t)bh * S_CACHE;
  const size_t row_out = (size_t)bh * SP1;
  const int pbase = (bh * NCH + chunk) * 68;

  // coalesced cache copy (32 keys x 64 dims, K and V), NT stores
  {
    const v4f* ksrc = (const v4f*)(k_in + (row_in + chunk * 32) * 64);
    const v4f* vsrc = (const v4f*)(v_in + (row_in + chunk * 32) * 64);
    v4f* kdst = (v4f*)(k_out + (row_out + chunk * 32) * 64);
    v4f* vdst = (v4f*)(v_out + (row_out + chunk * 32) * 64);
    const v4f kc0 = ksrc[t], kc1 = ksrc[t + 256];
    const v4f vc0 = vsrc[t], vc1 = vsrc[t + 256];
    __builtin_nontemporal_store(kc0, &kdst[t]);
    __builtin_nontemporal_store(kc1, &kdst[t + 256]);
    __builtin_nontemporal_store(vc0, &vdst[t]);
    __builtin_nontemporal_store(vc1, &vdst[t + 256]);
  }
  // q combine (+ k/v combine for new token)
  if (t < 64) {
    float s = 0.f;
#pragma unroll
    for (int ks = 0; ks < 16; ++ks)
      s += qkv_part[(size_t)(ks * 6 + b) * D + h * 64 + t];
    q[t] = s;
  } else if (hasNew && t < 128) {
    const int u = t - 64;
    float s = 0.f;
#pragma unroll
    for (int ks = 0; ks < 16; ++ks)
      s += qkv_part[(size_t)(ks * 6 + 2 + b) * D + h * 64 + u];
    kn[u] = s;
  } else if (hasNew && t < 192) {
    const int u = t - 128;
    float s = 0.f;
#pragma unroll
    for (int ks = 0; ks < 16; ++ks)
      s += qkv_part[(size_t)(ks * 6 + 4 + b) * D + h * 64 + u];
    vn[u] = s;
  }
  __syncthreads();
  {
    const float pos = (float)position[b];
    if (t < 32) {
      const float inv = expf(-(float)t * 0.28782313662425575f);  // ln(1e4)/32
      const float ang = pos * inv;
      const float c = cosf(ang), sn = sinf(ang);
      const float x1 = q[t], x2 = q[t + 32];
      q[t]      = (x1 * c - x2 * sn) * 0.125f;
      q[t + 32] = (x1 * sn + x2 * c) * 0.125f;
    } else if (hasNew && t < 64) {
      const int u = t - 32;
      const float inv = expf(-(float)u * 0.28782313662425575f);
      const float ang = pos * inv;
      const float c = cosf(ang), sn = sinf(ang);
      const float x1 = kn[u], x2 = kn[u + 32];
      kn[u]      = x1 * c - x2 * sn;
      kn[u + 32] = x1 * sn + x2 * c;
    }
  }
  __syncthreads();
  if (hasNew && t < 64) {
    k_out[(row_out + S_CACHE) * 64 + t] = kn[t];
    v_out[(row_out + S_CACHE) * 64 + t] = vn[t];
    float dp = q[t] * kn[t];
#pragma unroll
    for (int off = 32; off; off >>= 1) dp += __shfl_xor(dp, off);
    if (t == 0) msl[0] = dp;
  }
  // scores over 32 old keys (k_in re-read hits L1 after the copy loads)
  {
    const int key = t & 31, kp = t >> 5;
    const float* krow = k_in + (row_in + chunk * 32 + key) * 64 + kp * 8;
    const float4 k0 = *(const float4*)krow;
    const float4 k1 = *(const float4*)(krow + 4);
    const int d = kp * 8;
    float dp = k0.x*q[d] + k0.y*q[d+1] + k0.z*q[d+2] + k0.w*q[d+3]
             + k1.x*q[d+4] + k1.y*q[d+5] + k1.z*q[d+6] + k1.w*q[d+7];
    red8[kp][key] = dp;
  }
  __syncthreads();
  if (t < 32) {
    float score = 0.f;
#pragma unroll
    for (int k2 = 0; k2 < 8; ++k2) score += red8[k2][t];
    float m = score;
#pragma unroll
    for (int off = 16; off; off >>= 1) m = fmaxf(m, __shfl_xor(m, off));
    const float nsc = hasNew ? msl[0] : -1e30f;
    m = fmaxf(m, nsc);
    const float p = expf(score - m);
    float l = p;
#pragma unroll
    for (int off = 16; off; off >>= 1) l += __shfl_xor(l, off);
    sc[t] = p;
    if (t == 0) {
      const float pn = hasNew ? expf(nsc - m) : 0.f;
      sc[32] = pn; msl[1] = m; msl[2] = l + pn;
    }
  }
  __syncthreads();
  {
    const int d4 = (t & 15) * 4, sp = t >> 4;
    float ax = 0.f, ay = 0.f, az = 0.f, aw = 0.f;
#pragma unroll
    for (int r = 0; r < 2; ++r) {
      const int sl = sp * 2 + r;
      const float4 vv = *(const float4*)(v_in + (row_in + chunk * 32 + sl) * 64 + d4);
      const float p2 = sc[sl];
      ax += vv.x * p2; ay += vv.y * p2; az += vv.z * p2; aw += vv.w * p2;
    }
    pvred[sp][d4+0]=ax; pvred[sp][d4+1]=ay; pvred[sp][d4+2]=az; pvred[sp][d4+3]=aw;
  }
  __syncthreads();
  if (t < 64) {
    float a = 0.f;
#pragma unroll
    for (int s2 = 0; s2 < 16; ++s2) a += pvred[s2][t];
    if (hasNew) a += sc[32] * vn[t];
    attn_part[pbase + 2 + t] = a;
    if (t == 0) { attn_part[pbase + 0] = msl[1]; attn_part[pbase + 1] = msl[2]; }
  }
}

// ---------------------------------------------------------------------------
// O-proj. grid(8, 32): ks = 128-row K-range (2 heads), j-tile 32.
// Merges the 16 attention partials (softmax merge), then GEMV of wo.
// ---------------------------------------------------------------------------
__global__ __launch_bounds__(256) void k_oproj(
    const float* __restrict__ attn_part, const float* __restrict__ wo,
    float* __restrict__ oproj_part)
{
  __shared__ float o[2][128];
  __shared__ float cw[2][2][NCH];
  __shared__ float redg[32][2][32];
  const int t = threadIdx.x;
  const int ks = blockIdx.x;   // 0..7
  const int cg = blockIdx.y;   // 0..31
  const int ibeg = ks * 128;
  const int jbase = cg * 32;
  const int jo4 = (t & 7) * 4;
  const int kp = t >> 3;       // 0..31
  float4 wbuf[4];
#pragma unroll
  for (int r = 0; r < 4; ++r)
    wbuf[r] = *(const float4*)(wo + (size_t)(ibeg + kp * 4 + r) * D + jbase + jo4);
  if (t < 4) {
    const int bb = t >> 1, hr = t & 1;
    const int hh = ks * 2 + hr;
    const int base = ((bb * 16 + hh) * NCH) * 68;
    float mg = -1e30f;
    for (int c = 0; c < NCH; ++c) mg = fmaxf(mg, attn_part[base + c * 68]);
    float lg = 0.f;
    float wloc[NCH];
    for (int c = 0; c < NCH; ++c) {
      const float w = expf(attn_part[base + c * 68] - mg);
      wloc[c] = w;
      lg += attn_part[base + c * 68 + 1] * w;
    }
    const float invl = 1.f / lg;
    for (int c = 0; c < NCH; ++c) cw[bb][hr][c] = wloc[c] * invl;
  }
  __syncthreads();
  {
    const int bb = t >> 7, ir = t & 127;
    const int i = ibeg + ir;
    const int hh = i >> 6, hr = hh - ks * 2, d = i & 63;
    float s = 0.f;
#pragma unroll
    for (int c = 0; c < NCH; ++c)
      s += attn_part[((bb * 16 + hh) * NCH + c) * 68 + 2 + d] * cw[bb][hr][c];
    o[bb][ir] = s;
  }
  __syncthreads();
  float a00=0,a01=0,a02=0,a03=0, a10=0,a11=0,a12=0,a13=0;
#pragma unroll
  for (int r = 0; r < 4; ++r) {
    const int ir = kp * 4 + r;
    const float x0 = o[0][ir], x1 = o[1][ir];
    a00 += wbuf[r].x*x0; a01 += wbuf[r].y*x0; a02 += wbuf[r].z*x0; a03 += wbuf[r].w*x0;
    a10 += wbuf[r].x*x1; a11 += wbuf[r].y*x1; a12 += wbuf[r].z*x1; a13 += wbuf[r].w*x1;
  }
  redg[kp][0][jo4+0]=a00; redg[kp][0][jo4+1]=a01; redg[kp][0][jo4+2]=a02; redg[kp][0][jo4+3]=a03;
  redg[kp][1][jo4+0]=a10; redg[kp][1][jo4+1]=a11; redg[kp][1][jo4+2]=a12; redg[kp][1][jo4+3]=a13;
  __syncthreads();
  if (t < 64) {
    const int b = t >> 5, jo = t & 31;
    float s = 0.f;
#pragma unroll
    for (int k2 = 0; k2 < 32; ++k2) s += redg[k2][b][jo];
    oproj_part[(size_t)(ks * 2 + b) * D + jbase + jo] = s;
  }
}

// ---------------------------------------------------------------------------
// Gate+Up GEMV. grid(8, 64): ks = 128-row K-range, j-tile 64. Prologue
// combines oproj partials + residual + rmsnorm; writes raw h2 via block(0,0).
// ---------------------------------------------------------------------------
__global__ __launch_bounds__(256) void k_gateup(
    const float* __restrict__ hbase, const float* __restrict__ oproj_part,
    float* __restrict__ h2_out, const float* __restrict__ ln2,
    const float* __restrict__ wg, const float* __restrict__ wu,
    float* __restrict__ gu_part, float scale)
{
  __shared__ float hn[2][D];
  __shared__ float redg[16][4][64];
  const int t = threadIdx.x;
  const int ks = blockIdx.x;   // 0..7
  const int cg = blockIdx.y;   // 0..63
  const int jbase = cg * 64;
  const int jo4 = (t & 15) * 4;
  const int kp = t >> 4;
  const int ib = ks * 128 + kp * 8;
  float4 wgb[8];
#pragma unroll
  for (int r = 0; r < 8; ++r)
    wgb[r] = *(const float4*)(wg + (size_t)(ib + r) * DFF + jbase + jo4);
  prologue_norm(hbase, oproj_part, 8, scale, ln2, hn, h2_out);
  float g00=0,g01=0,g02=0,g03=0, g10=0,g11=0,g12=0,g13=0;
  float u00=0,u01=0,u02=0,u03=0, u10=0,u11=0,u12=0,u13=0;
#pragma unroll
  for (int r = 0; r < 8; ++r) {
    const float x0 = hn[0][ib + r], x1 = hn[1][ib + r];
    g00 += wgb[r].x*x0; g01 += wgb[r].y*x0; g02 += wgb[r].z*x0; g03 += wgb[r].w*x0;
    g10 += wgb[r].x*x1; g11 += wgb[r].y*x1; g12 += wgb[r].z*x1; g13 += wgb[r].w*x1;
  }
#pragma unroll
  for (int r = 0; r < 8; ++r) {
    const float4 c = *(const float4*)(wu + (size_t)(ib + r) * DFF + jbase + jo4);
    const float x0 = hn[0][ib + r], x1 = hn[1][ib + r];
    u00 += c.x*x0; u01 += c.y*x0; u02 += c.z*x0; u03 += c.w*x0;
    u10 += c.x*x1; u11 += c.y*x1; u12 += c.z*x1; u13 += c.w*x1;
  }
  redg[kp][0][jo4+0]=g00; redg[kp][0][jo4+1]=g01; redg[kp][0][jo4+2]=g02; redg[kp][0][jo4+3]=g03;
  redg[kp][1][jo4+0]=g10; redg[kp][1][jo4+1]=g11; redg[kp][1][jo4+2]=g12; redg[kp][1][jo4+3]=g13;
  redg[kp][2][jo4+0]=u00; redg[kp][2][jo4+1]=u01; redg[kp][2][jo4+2]=u02; redg[kp][2][jo4+3]=u03;
  redg[kp][3][jo4+0]=u10; redg[kp][3][jo4+1]=u11; redg[kp][3][jo4+2]=u12; redg[kp][3][jo4+3]=u13;
  __syncthreads();
  {
    const int sel = t >> 6;      // 0:g,b0 1:g,b1 2:u,b0 3:u,b1
    const int jo = t & 63;
    float s = 0.f;
#pragma unroll
    for (int k2 = 0; k2 < 16; ++k2) s += redg[k2][sel][jo];
    const int gm = sel >> 1, b = sel & 1;
    gu_part[(size_t)(ks * 4 + gm * 2 + b) * DFF + jbase + jo] = s;
  }
}

// ---------------------------------------------------------------------------
// Down GEMV. grid(8, 32): ks = 512-row K-range of DFF, j-tile 32.
// act = silu(g)*u combined from 8 gu splits.
// ---------------------------------------------------------------------------
__global__ __launch_bounds__(256) void k_down(
    const float* __restrict__ gu_part, const float* __restrict__ wd,
    float* __restrict__ down_part)
{
  __shared__ float act[2][512];
  __shared__ float redg[32][2][32];
  const int t = threadIdx.x;
  const int ks = blockIdx.x;   // 0..7
  const int cg = blockIdx.y;   // 0..31
  const int ibeg = ks * 512;
  const int jbase = cg * 32;
  const int jo4 = (t & 7) * 4;
  const int kp = t >> 3;       // 0..31
  const int ib = kp * 16;
  float4 wbuf[8];
#pragma unroll
  for (int r = 0; r < 8; ++r)
    wbuf[r] = *(const float4*)(wd + (size_t)(ibeg + ib + r) * D + jbase + jo4);
#pragma unroll
  for (int u = 0; u < 4; ++u) {
    const int e = u * 256 + t;
    const int b = e >> 9, ir = e & 511;
    const int i = ibeg + ir;
    float g = 0.f, uu = 0.f;
#pragma unroll
    for (int k = 0; k < 8; ++k) {
      g  += gu_part[(size_t)(k * 4 + b) * DFF + i];
      uu += gu_part[(size_t)(k * 4 + 2 + b) * DFF + i];
    }
    act[b][ir] = silu_f(g) * uu;
  }
  __syncthreads();
  float a00=0,a01=0,a02=0,a03=0, a10=0,a11=0,a12=0,a13=0;
#pragma unroll
  for (int r = 0; r < 8; ++r) {
    const float x0 = act[0][ib + r], x1 = act[1][ib + r];
    a00 += wbuf[r].x*x0; a01 += wbuf[r].y*x0; a02 += wbuf[r].z*x0; a03 += wbuf[r].w*x0;
    a10 += wbuf[r].x*x1; a11 += wbuf[r].y*x1; a12 += wbuf[r].z*x1; a13 += wbuf[r].w*x1;
  }
#pragma unroll
  for (int r = 8; r < 16; ++r) {
    const float4 w = *(const float4*)(wd + (size_t)(ibeg + ib + r) * D + jbase + jo4);
    const float x0 = act[0][ib + r], x1 = act[1][ib + r];
    a00 += w.x*x0; a01 += w.y*x0; a02 += w.z*x0; a03 += w.w*x0;
    a10 += w.x*x1; a11 += w.y*x1; a12 += w.z*x1; a13 += w.w*x1;
  }
  redg[kp][0][jo4+0]=a00; redg[kp][0][jo4+1]=a01; redg[kp][0][jo4+2]=a02; redg[kp][0][jo4+3]=a03;
  redg[kp][1][jo4+0]=a10; redg[kp][1][jo4+1]=a11; redg[kp][1][jo4+2]=a12; redg[kp][1][jo4+3]=a13;
  __syncthreads();
  if (t < 64) {
    const int b = t >> 5, jo = t & 31;
    float s = 0.f;
#pragma unroll
    for (int k2 = 0; k2 < 32; ++k2) s += redg[k2][b][jo];
    down_part[(size_t)(ks * 2 + b) * D + jbase + jo] = s;
  }
}

// ---------------------------------------------------------------------------
// Fused heads: blocks 0..127 stop-proj GEMV; blocks 128..143 FSQ head.
// Both start from lm_hidden = rmsnorm(h2 + scale*down, base_norm).
// ---------------------------------------------------------------------------
__global__ __launch_bounds__(256) void k_heads(
    const float* __restrict__ hbase, const float* __restrict__ down_part,
    const float* __restrict__ normw, const float* __restrict__ wsp,
    float* __restrict__ sproj_part,
    const float* __restrict__ fsq_in, const float* __restrict__ fsq_out,
    const float* __restrict__ embed,
    float* __restrict__ out_fsq, float* __restrict__ h_res, float scale)
{
  __shared__ float hn[2][D];
  const int t = threadIdx.x;
  const int bid = blockIdx.x;
  if (bid < 128) {
    __shared__ float redg[16][2][64];
    const int ks = bid >> 4, cg = bid & 15;
    const int jbase = cg * 64;
    const int jo4 = (t & 15) * 4;
    const int kp = t >> 4;
    const int ib = ks * 128 + kp * 8;
    float4 wbuf[8];
#pragma unroll
    for (int r = 0; r < 8; ++r)
      wbuf[r] = *(const float4*)(wsp + (size_t)(ib + r) * D + jbase + jo4);
    prologue_norm(hbase, down_part, 8, scale, normw, hn, nullptr);
    float a00=0,a01=0,a02=0,a03=0, a10=0,a11=0,a12=0,a13=0;
#pragma unroll
    for (int r = 0; r < 8; ++r) {
      const float x0 = hn[0][ib + r], x1 = hn[1][ib + r];
      a00 += wbuf[r].x*x0; a01 += wbuf[r].y*x0; a02 += wbuf[r].z*x0; a03 += wbuf[r].w*x0;
      a10 += wbuf[r].x*x1; a11 += wbuf[r].y*x1; a12 += wbuf[r].z*x1; a13 += wbuf[r].w*x1;
    }
    redg[kp][0][jo4+0]=a00; redg[kp][0][jo4+1]=a01; redg[kp][0][jo4+2]=a02; redg[kp][0][jo4+3]=a03;
    redg[kp][1][jo4+0]=a10; redg[kp][1][jo4+1]=a11; redg[kp][1][jo4+2]=a12; redg[kp][1][jo4+3]=a13;
    __syncthreads();
    if (t < 128) {
      const int b = t >> 6, jo = t & 63;
      float s = 0.f;
#pragma unroll
      for (int k2 = 0; k2 < 16; ++k2) s += redg[k2][b][jo];
      sproj_part[(size_t)(ks * 2 + b) * D + jbase + jo] = s;
    }
  } else {
    __shared__ float zred[4][2][32];
    __shared__ float zq[2][32];
    prologue_norm(hbase, down_part, 8, scale, normw, hn, nullptr);
    {
      const int c = t & 31, b = (t >> 5) & 1, kp = t >> 6;
      float s = 0.f;
      for (int i = kp * 256; i < kp * 256 + 256; ++i) s += hn[b][i] * fsq_in[i * 32 + c];
      zred[kp][b][c] = s;
    }
    __syncthreads();
    if (t < 64) {
      const int b = t >> 5, c = t & 31;
      float z = zred[0][b][c] + zred[1][b][c] + zred[2][b][c] + zred[3][b][c];
      z = tanhf(z);
      zq[b][c] = rintf(z * 3.5f) / 3.5f;
    }
    __syncthreads();
    if (t < 128) {
      const int b = t >> 6, jo = t & 63;
      const int j = (bid - 128) * 64 + jo;
      float s = 0.f;
#pragma unroll
      for (int c = 0; c < 32; ++c) s += zq[b][c] * fsq_out[c * D + j];
      out_fsq[b * D + j] = s;
      h_res[b * D + j] = s + embed[b * D + j];
    }
  }
}

// ---------------------------------------------------------------------------
__global__ __launch_bounds__(256) void k_stophead(
    const float* __restrict__ sproj_part, const float* __restrict__ bvec,
    const float* __restrict__ hw, const float* __restrict__ hb,
    float* __restrict__ out_stop)
{
  const int t = threadIdx.x;
  float acc0 = 0.f, acc1 = 0.f;
  for (int j = t; j < D; j += 256) {
    float v0 = bvec[j], v1 = bvec[j];
#pragma unroll
    for (int ks = 0; ks < 8; ++ks) {
      v0 += sproj_part[(ks * 2 + 0) * D + j];
      v1 += sproj_part[(ks * 2 + 1) * D + j];
    }
    acc0 += silu_f(v0) * hw[j];
    acc1 += silu_f(v1) * hw[j];
  }
  __shared__ float red[256];
  red[t] = acc0;
  __syncthreads();
  for (int s = 128; s > 0; s >>= 1) { if (t < s) red[t] += red[t + s]; __syncthreads(); }
  if (t == 0) out_stop[0] = red[0] + hb[0];
  __syncthreads();
  red[t] = acc1;
  __syncthreads();
  for (int s = 128; s > 0; s >>= 1) { if (t < s) red[t] += red[t + s]; __syncthreads(); }
  if (t == 0) out_stop[1] = red[0] + hb[0];
}

// ---------------------------------------------------------------------------
__global__ __launch_bounds__(256) void k_final(
    const float* __restrict__ hbase, const float* __restrict__ down_part,
    const float* __restrict__ normw, float* __restrict__ out_rh, float scale)
{
  __shared__ float hn[2][D];
  prologue_norm(hbase, down_part, 8, scale, normw, hn, nullptr);
  const int t = threadIdx.x;
  const int b = t >> 7;
  const int i0 = (t & 127) * 8;
#pragma unroll
  for (int u = 0; u < 8; ++u) out_rh[b * D + i0 + u] = hn[b][i0 + u];
}

// ---------------------------------------------------------------------------
extern "C" void kernel_launch(void* const* d_in, const int* in_sizes, int n_in,
                              void* d_out, int out_size, void* d_ws, size_t ws_size,
                              hipStream_t stream) {
  const float* embed      = (const float*)d_in[0];
  const int*   position   = (const int*)d_in[1];
  const float* base_k     = (const float*)d_in[2];
  const float* base_v     = (const float*)d_in[3];
  const float* res_k      = (const float*)d_in[4];
  const float* res_v      = (const float*)d_in[5];
  const float* base_ln1   = (const float*)d_in[6];
  const float* base_ln2   = (const float*)d_in[7];
  const float* base_wq    = (const float*)d_in[8];
  const float* base_wk    = (const float*)d_in[9];
  const float* base_wv    = (const float*)d_in[10];
  const float* base_wo    = (const float*)d_in[11];
  const float* base_wg    = (const float*)d_in[12];
  const float* base_wu    = (const float*)d_in[13];
  const float* base_wd    = (const float*)d_in[14];
  const float* base_norm  = (const float*)d_in[15];
  const float* res_ln1    = (const float*)d_in[16];
  const float* res_ln2    = (const float*)d_in[17];
  const float* res_wq     = (const float*)d_in[18];
  const float* res_wk     = (const float*)d_in[19];
  const float* res_wv     = (const float*)d_in[20];
  const float* res_wo     = (const float*)d_in[21];
  const float* res_wg     = (const float*)d_in[22];
  const float* res_wu     = (const float*)d_in[23];
  const float* res_wd     = (const float*)d_in[24];
  const float* res_norm   = (const float*)d_in[25];
  const float* fsq_in     = (const float*)d_in[26];
  const float* fsq_out    = (const float*)d_in[27];
  const float* stop_proj_w = (const float*)d_in[28];
  const float* stop_proj_b = (const float*)d_in[29];
  const float* stop_head_w = (const float*)d_in[30];
  const float* stop_head_b = (const float*)d_in[31];

  float* out = (float*)d_out;
  float* ws = (float*)d_ws;
  float* W_h     = ws + WS_H;
  float* W_h2    = ws + WS_H2;
  float* W_qkv   = ws + WS_QKV;
  float* W_attn  = ws + WS_ATTN;
  float* W_oproj = ws + WS_OPROJ;
  float* W_gu    = ws + WS_GU;
  float* W_down  = ws + WS_DOWN;
  float* W_sproj = ws + WS_SPROJ;

  const size_t cacheL_in  = (size_t)2 * NHEADS * S_CACHE * DH;   // 1048576
  const size_t cacheL_out = (size_t)2 * NHEADS * SP1 * DH;       // 1050624
  float* out_fsq  = out;
  float* out_rh   = out + 2048;
  float* out_stop = out + 4096;
  float* out_bnk  = out + 4098;
  float* out_bnv  = out_bnk + (size_t)NB_L * cacheL_out;
  float* out_rnk  = out_bnv + (size_t)NB_L * cacheL_out;
  float* out_rnv  = out_rnk + (size_t)NR_L * cacheL_out;

  const float scaleB = 1.4f / sqrtf((float)NB_L);
  const float scaleR = 1.4f / sqrtf((float)NR_L);

  auto run_layer = [&](const float* hbase, float* hout,
                       const float* ln1, const float* ln2,
                       const float* wq, const float* wk, const float* wv,
                       const float* wo, const float* wg, const float* wu,
                       const float* wd,
                       const float* kin, const float* vin,
                       float* kout, float* vout,
                       float scale, int has_prev) {
    k_qkv<<<dim3(16, 48), 256, 0, stream>>>(hbase, W_down, hout, ln1,
                                            wq, wk, wv, W_qkv, scale, has_prev);
    k_attn<<<dim3(NCH, 32), 256, 0, stream>>>(W_qkv, position, kin, vin, kout, vout, W_attn);
    k_oproj<<<dim3(8, 32), 256, 0, stream>>>(W_attn, wo, W_oproj);
    k_gateup<<<dim3(8, 64), 256, 0, stream>>>(W_h, W_oproj, W_h2, ln2, wg, wu, W_gu, scale);
    k_down<<<dim3(8, 32), 256, 0, stream>>>(W_gu, wd, W_down);
  };

  for (int l = 0; l < NB_L; ++l) {
    run_layer(l == 0 ? embed : W_h2, W_h,
              base_ln1 + (size_t)l * D, base_ln2 + (size_t)l * D,
              base_wq + (size_t)l * D * D, base_wk + (size_t)l * D * D,
              base_wv + (size_t)l * D * D, base_wo + (size_t)l * D * D,
              base_wg + (size_t)l * D * DFF, base_wu + (size_t)l * D * DFF,
              base_wd + (size_t)l * DFF * D,
              base_k + (size_t)l * cacheL_in, base_v + (size_t)l * cacheL_in,
              out_bnk + (size_t)l * cacheL_out, out_bnv + (size_t)l * cacheL_out,
              scaleB, l > 0);
  }

  k_heads<<<144, 256, 0, stream>>>(W_h2, W_down, base_norm, stop_proj_w, W_sproj,
                                   fsq_in, fsq_out, embed, out_fsq, W_h, scaleB);
  k_stophead<<<1, 256, 0, stream>>>(W_sproj, stop_proj_b, stop_head_w, stop_head_b, out_stop);

  for (int l = 0; l < NR_L; ++l) {
    run_layer(l == 0 ? W_h : W_h2, l == 0 ? nullptr : W_h,
              res_ln1 + (size_t)l * D, res_ln2 + (size_t)l * D,
              res_wq + (size_t)l * D * D, res_wk + (size_t)l * D * D,
              res_wv + (size_t)l * D * D, res_wo + (size_t)l * D * D,
              res_wg + (size_t)l * D * DFF, res_wu + (size_t)l * D * DFF,
              res_wd + (size_t)l * DFF * D,
              res_k + (size_t)l * cacheL_in, res_v + (size_t)l * cacheL_in,
              out_rnk + (size_t)l * cacheL_out, out_rnv + (size_t)l * cacheL_out,
              scaleR, l > 0);
  }

  k_final<<<1, 256, 0, stream>>>(W_h2, W_down, res_norm, out_rh, scaleR);
}